// Round 7
// baseline (1812.381 us; speedup 1.0000x reference)
//
#include <hip/hip_runtime.h>
#include <cfloat>

// Problem constants (match reference setup_inputs)
constexpr int NB = 8, NN = 3000, NM = 3000, KK = 8;
constexpr int CAP = 48;                       // per-row/col sparse capacity (padded)
constexpr float SCALE   = 14.426950408889634f;   // 1/(EPS*ln2), EPS=0.1
constexpr float UNSCALE = 0.06931471805599453f;  // EPS*ln2
constexpr float THRESH  = 0.1f;
constexpr unsigned DUMMY_PAT = 0x7f7f7f7fu;   // memset pattern: val=3.39e38 -> exp2()==0

// Sinkhorn geometry: 8 blocks/batch, wave w <-> producer-slice w (1:1)
constexpr int BPB  = 8;
constexpr int NBLK = NB * BPB;                // 64 blocks
constexpr int TPB  = 512;                     // 8 waves
constexpr int RPB  = NN / BPB;                // 375 rows per block

#if __has_builtin(__builtin_amdgcn_exp2f)
#define FEXP2(x) __builtin_amdgcn_exp2f(x)
#else
#define FEXP2(x) exp2f(x)
#endif
#if __has_builtin(__builtin_amdgcn_logf)
#define FLOG2(x) __builtin_amdgcn_logf(x)   // v_log_f32 = log2
#else
#define FLOG2(x) __log2f(x)
#endif

// Relaxed agent-scope atomics: plain coherence-point accesses, NO cache
// flushes (acquire/release at agent scope emit buffer_inv/buffer_wbl2 — the
// R2 disaster). Bypass L0/L1 — used ONLY for cross-block mutable data.
__device__ __forceinline__ float aloadf(const float* p) {
  return __hip_atomic_load(p, __ATOMIC_RELAXED, __HIP_MEMORY_SCOPE_AGENT);
}
__device__ __forceinline__ void astoref(float* p, float x) {
  __hip_atomic_store(p, x, __ATOMIC_RELAXED, __HIP_MEMORY_SCOPE_AGENT);
}
__device__ __forceinline__ int aloadi(const int* p) {
  return __hip_atomic_load(p, __ATOMIC_RELAXED, __HIP_MEMORY_SCOPE_AGENT);
}
__device__ __forceinline__ void astorei(int* p, int x) {
  __hip_atomic_store(p, x, __ATOMIC_RELAXED, __HIP_MEMORY_SCOPE_AGENT);
}

// ---------------------------------------------------------------------------
// K1: row L2 norms (as inverse) + top-8 smallest per row.
// 8 rows/block, 32 lanes/row. Per-lane register top-8 (stable: each lane's
// float4 indices ascend), then 5 rounds of shfl_xor sorted-8 merge using the
// bitonic min-trick: min(A[i], Brev[i]) holds the 8 smallest; 3-stage cleaner
// re-sorts. Lexicographic (val, idx) comparator == lax.top_k tie semantics.
// ---------------------------------------------------------------------------
__global__ __launch_bounds__(256) void k_rowprep(const float* __restrict__ C,
                                                 float* __restrict__ invnorms,
                                                 int* __restrict__ rowsel) {
  const int bn = blockIdx.x * 8 + (threadIdx.x >> 5);   // row id, 8 per block
  const int l  = threadIdx.x & 31;
  const float4* row4 = reinterpret_cast<const float4*>(C + (size_t)bn * NM);

  float tv[8]; int ti[8];
#pragma unroll
  for (int q = 0; q < 8; ++q) { tv[q] = FLT_MAX; ti[q] = 0x7fffffff; }
  float sq = 0.f;
  for (int c = 0; c < 24; ++c) {              // 750 float4 / 32 lanes
    int i = l + 32 * c;
    if (i < NM / 4) {
      float4 f = row4[i];
      sq += f.x * f.x + f.y * f.y + f.z * f.z + f.w * f.w;
      float e[4] = { f.x, f.y, f.z, f.w };
#pragma unroll
      for (int j = 0; j < 4; ++j) {
        float v = e[j];
        if (v < tv[7]) {                      // stable: strict <, asc indices
          int idx = 4 * i + j;
          int pos = 8;
#pragma unroll
          for (int q = 7; q >= 0; --q) if (v < tv[q]) pos = q;
#pragma unroll
          for (int q = 7; q >= 1; --q) if (q > pos) { tv[q] = tv[q-1]; ti[q] = ti[q-1]; }
#pragma unroll
          for (int q = 0; q < 8; ++q) if (q == pos) { tv[q] = v; ti[q] = idx; }
        }
      }
    }
  }
  // norm reduce within the 32-lane row group
#pragma unroll
  for (int o = 16; o; o >>= 1) sq += __shfl_down(sq, o, 32);

  // 5-round sorted-merge across 32 lanes (xor masks stay within the group)
#pragma unroll
  for (int msk = 1; msk <= 16; msk <<= 1) {
    float pv[8]; int pi[8];
#pragma unroll
    for (int q = 0; q < 8; ++q) { pv[q] = __shfl_xor(tv[q], msk); pi[q] = __shfl_xor(ti[q], msk); }
    float mv[8]; int mi[8];
#pragma unroll
    for (int q = 0; q < 8; ++q) {             // min with reversed partner
      float av = tv[q], bv = pv[7 - q];
      int   ai = ti[q], bi = pi[7 - q];
      bool ta = (av < bv) || (av == bv && ai < bi);
      mv[q] = ta ? av : bv; mi[q] = ta ? ai : bi;
    }
    auto ce = [&](int i, int j) {             // compare-exchange (val,idx) lex
      bool sw = (mv[i] > mv[j]) || (mv[i] == mv[j] && mi[i] > mi[j]);
      float fv = sw ? mv[j] : mv[i], gv = sw ? mv[i] : mv[j];
      int   fi = sw ? mi[j] : mi[i], gi = sw ? mi[i] : mi[j];
      mv[i] = fv; mv[j] = gv; mi[i] = fi; mi[j] = gi;
    };
    ce(0,4); ce(1,5); ce(2,6); ce(3,7);       // bitonic 3-stage cleaner
    ce(0,2); ce(1,3); ce(4,6); ce(5,7);
    ce(0,1); ce(2,3); ce(4,5); ce(6,7);
#pragma unroll
    for (int q = 0; q < 8; ++q) { tv[q] = mv[q]; ti[q] = mi[q]; }
  }

  if (l == 0) {
#pragma unroll
    for (int q = 0; q < 8; ++q) rowsel[(size_t)bn * KK + q] = ti[q];
    float nm = sqrtf(sq);
    invnorms[bn] = 1.0f / fmaxf(nm, 1e-12f);
  }
}

// ---------------------------------------------------------------------------
// K2: per-column top-8 largest of C/norm. Tile = 256 cols (lane owns 4 via
// float4 -> each wave reads 1 KB contiguous per row). 4 waves = 4 row-chunks
// of 750. Register lists, LDS merge (tournament w/ used-mask, validated).
// ---------------------------------------------------------------------------
__global__ __launch_bounds__(256) void k_coltop(const float* __restrict__ C,
                                                const float* __restrict__ invnorms,
                                                int* __restrict__ colsel) {
  const int b = blockIdx.y, cg = blockIdx.x;  // cg 0..11
  const int tid = threadIdx.x;
  const int w = tid >> 6, l = tid & 63;       // wave = row-chunk
  const int g4 = cg * 64 + l;                 // float4-group, valid < 750
  __shared__ float sv[4][256][8];             // 32 KB
  __shared__ int   si[4][256][8];             // 32 KB

  float tv[4][8]; int ti[4][8];
#pragma unroll
  for (int j = 0; j < 4; ++j)
#pragma unroll
    for (int q = 0; q < 8; ++q) { tv[j][q] = -FLT_MAX; ti[j][q] = 0x7fffffff; }

  if (g4 < NM / 4) {
    const float4* base = reinterpret_cast<const float4*>(
        C + ((size_t)b * NN + (size_t)w * 750) * NM) + g4;
    const float* ivn = invnorms + (size_t)b * NN + w * 750;
#pragma unroll 5
    for (int rr = 0; rr < 750; ++rr) {
      float4 f = base[(size_t)rr * (NM / 4)];
      float iv = ivn[rr];                     // wave-uniform -> scalar load
      float e[4] = { f.x * iv, f.y * iv, f.z * iv, f.w * iv };
      int idx = w * 750 + rr;
#pragma unroll
      for (int j = 0; j < 4; ++j) {
        float v = e[j];
        if (v > tv[j][7]) {                   // stable: strict >, asc rows
          int pos = 8;
#pragma unroll
          for (int q = 7; q >= 0; --q) if (v > tv[j][q]) pos = q;
#pragma unroll
          for (int q = 7; q >= 1; --q) if (q > pos) { tv[j][q] = tv[j][q-1]; ti[j][q] = ti[j][q-1]; }
#pragma unroll
          for (int q = 0; q < 8; ++q) if (q == pos) { tv[j][q] = v; ti[j][q] = idx; }
        }
      }
    }
  }
#pragma unroll
  for (int j = 0; j < 4; ++j)
#pragma unroll
    for (int q = 0; q < 8; ++q) { sv[w][l * 4 + j][q] = tv[j][q]; si[w][l * 4 + j][q] = ti[j][q]; }
  __syncthreads();

  int m = cg * 256 + tid;                     // one thread per tile column
  if (m < NM) {
    unsigned used = 0;
    for (int p = 0; p < KK; ++p) {
      float bv = -FLT_MAX; int bi = 0x7fffffff; int bq = 0;
#pragma unroll
      for (int c = 0; c < 4; ++c)
#pragma unroll
        for (int q = 0; q < 8; ++q) {
          int bit = c * 8 + q;
          if ((used >> bit) & 1u) continue;
          float v = sv[c][tid][q];
          int   n = si[c][tid][q];
          if (v > bv || (v == bv && n < bi)) { bv = v; bi = n; bq = bit; }
        }
      used |= 1u << bq;
      colsel[((size_t)b * NM + m) * KK + p] = bi;
    }
  }
}

// ---------------------------------------------------------------------------
// K3 (fused fill): base slots 0..7 of CSR/CSC + non-duplicate extras (8+).
// pk arrays are pre-filled with DUMMY_PAT via hipMemsetD32Async, so base and
// extra writes touch disjoint slot ranges -> no race, one kernel.
// ---------------------------------------------------------------------------
__global__ __launch_bounds__(256) void k_fill(const float* __restrict__ C,
    const float* __restrict__ invnorms, const int* __restrict__ rowsel,
    const int* __restrict__ colsel, int* r_cnt, int* c_cnt,
    int2* __restrict__ r_pk, int2* __restrict__ c_pk) {
  int t = blockIdx.x * 256 + threadIdx.x;
  if (t >= NB * NN * KK) return;
  int k = t % KK; int bn = t / KK;
  int b = bn / NN; int n = bn % NN;
  {  // base row entry
    int m = rowsel[t];
    float v2 = C[((size_t)b * NN + n) * NM + m] * invnorms[bn] * SCALE;
    r_pk[(size_t)bn * CAP + k] = make_int2(m, __float_as_int(v2));
  }
  {  // base col entry (bn reinterpreted as b*NM+m)
    int m2 = n;
    int n2 = colsel[t];
    float v2 = C[((size_t)b * NN + n2) * NM + m2] * invnorms[(size_t)b * NN + n2] * SCALE;
    c_pk[(size_t)bn * CAP + k] = make_int2(n2, __float_as_int(v2));
  }
  int m = n;                                  // extras: t = (b*NM+m)*KK + k
  {  // colsel entry (b,m,k): row n3 gains column m unless duplicate
    int n3 = colsel[t];
    const int* rs = rowsel + ((size_t)b * NN + n3) * KK;
    bool dup = false;
#pragma unroll
    for (int q = 0; q < KK; ++q) dup |= (rs[q] == m);
    if (!dup) {
      int slot = 8 + atomicAdd(&r_cnt[(size_t)b * NN + n3], 1);
      if (slot < CAP) {
        float v2 = C[((size_t)b * NN + n3) * NM + m] * invnorms[(size_t)b * NN + n3] * SCALE;
        r_pk[((size_t)b * NN + n3) * CAP + slot] = make_int2(m, __float_as_int(v2));
      }
    }
  }
  {  // rowsel entry (b,n2,k): column mm gains row n2 unless duplicate
    int n2 = m;
    int mm = rowsel[t];
    const int* cs = colsel + ((size_t)b * NM + mm) * KK;
    bool dup = false;
#pragma unroll
    for (int q = 0; q < KK; ++q) dup |= (cs[q] == n2);
    if (!dup) {
      int slot = 8 + atomicAdd(&c_cnt[(size_t)b * NM + mm], 1);
      if (slot < CAP) {
        float v2 = C[((size_t)b * NN + n2) * NM + mm] * invnorms[(size_t)b * NN + n2] * SCALE;
        c_pk[((size_t)b * NM + mm) * CAP + slot] = make_int2(n2, __float_as_int(v2));
      }
    }
  }
}

// ---------------------------------------------------------------------------
// K5: pull-as-ready sparse Sinkhorn (validated R6 structure, unchanged except
// prologue clamp for memset-dummies). 8 blocks/batch; wave w pulls producer
// w's slice when its stamp shows. U/V parity double-buffered (reuse distance
// 2 => no overwrite race). Error partials ride the U stamps; every block sums
// the same 8 floats in fixed order -> deterministic uniform break.
// ---------------------------------------------------------------------------
__global__ __launch_bounds__(TPB, 1) void k_sink_coop(
    const float* __restrict__ mu, const float* __restrict__ nu,
    const int2* __restrict__ r_pk, const int2* __restrict__ c_pk,
    float* __restrict__ Upub, float* __restrict__ Vpub,
    int* stU, int* stV, float* errW, float* __restrict__ costpart) {
  const int blk = blockIdx.x;
  const int b = blk % NB, slice = blk / NB;   // %8: batch pinned per XCD (heuristic)
  const int tid = threadIdx.x;
  const int w = tid >> 6, lane = tid & 63;
  const int r = slice * RPB + tid;
  const bool has_r = (tid < RPB);             // NN == NM: same geometry

  // wave-resident sparse entries (persistent VGPRs)
  float rval[CAP], cval[CAP];
  unsigned ridx[CAP / 2], cidx[CAP / 2];
  float u = 0.f, vv = 0.f, lmu = 0.f, lnu = 0.f;
  if (has_r) {
    const int2* rp = r_pk + ((size_t)b * NN + r) * CAP;
    const int2* cp = c_pk + ((size_t)b * NM + r) * CAP;
#pragma unroll
    for (int i = 0; i < CAP; i += 2) {
      int2 e0 = rp[i], e1 = rp[i + 1];
      rval[i] = __int_as_float(e0.y); rval[i + 1] = __int_as_float(e1.y);
      unsigned i0 = min((unsigned)e0.x & 0xFFFFu, (unsigned)(NN - 1));  // clamp dummies
      unsigned i1 = min((unsigned)e1.x & 0xFFFFu, (unsigned)(NN - 1));
      ridx[i / 2] = i0 | (i1 << 16);
      int2 f0 = cp[i], f1 = cp[i + 1];
      cval[i] = __int_as_float(f0.y); cval[i + 1] = __int_as_float(f1.y);
      unsigned j0 = min((unsigned)f0.x & 0xFFFFu, (unsigned)(NN - 1));
      unsigned j1 = min((unsigned)f1.x & 0xFFFFu, (unsigned)(NN - 1));
      cidx[i / 2] = j0 | (j1 << 16);
    }
    lmu = FLOG2(mu[(size_t)b * NN + r] + 1e-8f);
    lnu = FLOG2(nu[(size_t)b * NM + r] + 1e-8f);
  }

  __shared__ float XL[NN];                    // staged U or V (12 KB)
  __shared__ float sred[TPB / 64];
  __shared__ float errl[BPB];
  int*   stUb = stU + b * BPB * 16;
  int*   stVb = stV + b * BPB * 16;
  int itf = 0;
  bool done = false;

  for (int it = 0; it < 100; ++it) {
    // ---- stage-A: V(it-1) (zeros at it==0), wave w pulls producer w ----
    if (it == 0) {
      for (int i = tid; i < NN; i += TPB) XL[i] = 0.f;
    } else {
      const float* src = Vpub + (size_t)((it - 1) & 1) * (NB * NN) + (size_t)b * NN;
      const int* st = stVb + w * 16;
      while (aloadi(st) < it) __builtin_amdgcn_s_sleep(1);   // wave-uniform
      for (int i = lane; i < RPB; i += 64)
        XL[w * RPB + i] = aloadf(&src[w * RPB + i]);
    }
    __syncthreads();

    // ---- compute-A: u update, publish U + err ----
    float errp = 0.f;
    if (has_r) {
      float s = 0.f;
#pragma unroll
      for (int i = 0; i < CAP; ++i) {
        int ix = (ridx[i >> 1] >> ((i & 1) * 16)) & 0xFFFF;
        s += FEXP2(u + XL[ix] - rval[i]);
      }
      float un = lmu - FLOG2(1e-8f + s) + u;
      errp = fabsf(un - u);
      u = un;
      astoref(&Upub[(size_t)(it & 1) * (NB * NN) + (size_t)b * NN + r], u);
    }
#pragma unroll
    for (int o = 32; o; o >>= 1) errp += __shfl_down(errp, o);
    if (lane == 0) sred[w] = errp;
    __syncthreads();                          // drains ALL waves' U stores too
    if (tid == 0) {
      float e = sred[0] + sred[1] + sred[2] + sred[3]
              + sred[4] + sred[5] + sred[6] + sred[7];
      astoref(&errW[(size_t)((it & 1) * NB + b) * BPB * 16 + slice * 16], e);
      asm volatile("s_waitcnt vmcnt(0)" ::: "memory");
      astorei(&stUb[slice * 16], it + 1);
    }

    // ---- stage-B: U(it), wave w pulls producer w + its err word ----
    {
      const float* src = Upub + (size_t)(it & 1) * (NB * NN) + (size_t)b * NN;
      const int* st = stUb + w * 16;
      while (aloadi(st) < it + 1) __builtin_amdgcn_s_sleep(1);
      for (int i = lane; i < RPB; i += 64)
        XL[w * RPB + i] = aloadf(&src[w * RPB + i]);
      if (lane == 0)
        errl[w] = aloadf(&errW[(size_t)((it & 1) * NB + b) * BPB * 16 + w * 16]);
    }
    __syncthreads();

    // ---- compute-B: v update, publish V; uniform done decision ----
    float errtot = errl[0] + errl[1] + errl[2] + errl[3]
                 + errl[4] + errl[5] + errl[6] + errl[7];   // fixed order
    done = (errtot * UNSCALE < THRESH);
    if (has_r) {
      float s = 0.f;
#pragma unroll
      for (int i = 0; i < CAP; ++i) {
        int ix = (cidx[i >> 1] >> ((i & 1) * 16)) & 0xFFFF;
        s += FEXP2(vv + XL[ix] - cval[i]);
      }
      vv = lnu - FLOG2(1e-8f + s) + vv;
      astoref(&Vpub[(size_t)(it & 1) * (NB * NN) + (size_t)b * NN + r], vv);
    }
    __syncthreads();                          // drain all V stores
    if (tid == 0) astorei(&stVb[slice * 16], it + 1);
    itf = it;
    if (done) break;                          // uniform across the batch
  }

  // ---- epilogue: stage final V(itf), cost partial over own rows ----
  {
    const float* src = Vpub + (size_t)(itf & 1) * (NB * NN) + (size_t)b * NN;
    const int* st = stVb + w * 16;
    while (aloadi(st) < itf + 1) __builtin_amdgcn_s_sleep(1);
    for (int i = lane; i < RPB; i += 64)
      XL[w * RPB + i] = aloadf(&src[w * RPB + i]);
  }
  __syncthreads();
  float cs = 0.f;
  if (has_r) {
#pragma unroll
    for (int i = 0; i < CAP; ++i) {
      int ix = (ridx[i >> 1] >> ((i & 1) * 16)) & 0xFFFF;
      float val = rval[i];
      cs += FEXP2(u + XL[ix] - val) * val;    // dummies give exp2(-huge)*big = 0
    }
  }
#pragma unroll
  for (int o = 32; o; o >>= 1) cs += __shfl_down(cs, o);
  if (lane == 0) sred[w] = cs;
  __syncthreads();
  if (tid == 0)
    costpart[b * BPB + slice] = sred[0] + sred[1] + sred[2] + sred[3]
                              + sred[4] + sred[5] + sred[6] + sred[7];
}

// Deterministic final reduction: fixed-order sums.
__global__ void k_final2(const float* __restrict__ costpart, float* __restrict__ out) {
  if (threadIdx.x == 0 && blockIdx.x == 0) {
    float tot = 0.f;
    for (int b = 0; b < NB; ++b) {
      float cb = 0.f;
      for (int s = 0; s < BPB; ++s) cb += costpart[b * BPB + s];
      tot += cb * UNSCALE;
    }
    out[0] = tot * (1.0f / NB);
  }
}

// ---------------------------------------------------------------------------
extern "C" void kernel_launch(void* const* d_in, const int* in_sizes, int n_in,
                              void* d_out, int out_size, void* d_ws, size_t ws_size,
                              hipStream_t stream) {
  const float* mu = (const float*)d_in[0];
  const float* nu = (const float*)d_in[1];
  const float* C  = (const float*)d_in[2];
  float* out = (float*)d_out;

  char* ws = (char*)d_ws;
  size_t off = 0;
  auto alloc = [&](size_t bytes) {
    void* p = ws + off;
    off += (bytes + 255) & ~(size_t)255;
    return p;
  };
  float* invnorms = (float*)alloc(sizeof(float) * NB * NN);
  int*   rowsel   = (int*)  alloc(sizeof(int)   * NB * NN * KK);
  int*   colsel   = (int*)  alloc(sizeof(int)   * NB * NM * KK);
  int2*  r_pk     = (int2*) alloc(sizeof(int2)  * NB * NN * CAP);  // 9,216,000 B
  int2*  c_pk     = (int2*) alloc(sizeof(int2)  * NB * NM * CAP);  // contiguous
  float* Upub     = (float*)alloc(sizeof(float) * 2 * NB * NN);    // parity dbuf
  float* Vpub     = (float*)alloc(sizeof(float) * 2 * NB * NM);
  // ---- zeroed region starts here ----
  int*   r_cnt    = (int*)  alloc(sizeof(int)   * NB * NN);
  int*   c_cnt    = (int*)  alloc(sizeof(int)   * NB * NM);
  int*   stU      = (int*)  alloc(sizeof(int)   * NB * BPB * 16);
  int*   stV      = (int*)  alloc(sizeof(int)   * NB * BPB * 16);
  float* errW     = (float*)alloc(sizeof(float) * 2 * NB * BPB * 16);
  float* costpart = (float*)alloc(sizeof(float) * NB * BPB);
  (void)ws_size; (void)in_sizes; (void)n_in; (void)out_size;

  // pk arrays pre-filled with dummy pattern (val=3.39e38, idx clamped in sink)
  hipMemsetD32Async((hipDeviceptr_t)r_pk, (int)DUMMY_PAT,
                    (size_t)2 * NB * NN * CAP * 2, stream);
  size_t span = (size_t)((char*)costpart - (char*)r_cnt)
              + ((sizeof(float) * NB * BPB + 255) & ~(size_t)255);
  hipMemsetAsync(r_cnt, 0, span, stream);     // r_cnt..costpart (stamps -> 0)

  hipLaunchKernelGGL(k_rowprep, dim3(NB * NN / 8), dim3(256), 0, stream,
                     C, invnorms, rowsel);
  hipLaunchKernelGGL(k_coltop, dim3(12, NB), dim3(256), 0, stream,
                     C, invnorms, colsel);
  int nthreads = NB * NN * KK;
  hipLaunchKernelGGL(k_fill, dim3((nthreads + 255) / 256), dim3(256), 0, stream,
                     C, invnorms, rowsel, colsel, r_cnt, c_cnt, r_pk, c_pk);

  void* args[] = { (void*)&mu, (void*)&nu, (void*)&r_pk, (void*)&c_pk,
                   (void*)&Upub, (void*)&Vpub, (void*)&stU, (void*)&stV,
                   (void*)&errW, (void*)&costpart };
  hipLaunchCooperativeKernel((const void*)k_sink_coop, dim3(NBLK), dim3(TPB),
                             args, 0, stream);

  hipLaunchKernelGGL(k_final2, dim3(1), dim3(64), 0, stream, costpart, out);
}

// Round 8
// 1280.274 us; speedup vs baseline: 1.4156x; 1.4156x over previous
//
#include <hip/hip_runtime.h>
#include <cfloat>

// Problem constants (match reference setup_inputs)
constexpr int NB = 8, NN = 3000, NM = 3000, KK = 8;
constexpr int CAP = 48;                       // per-row/col sparse capacity (padded)
constexpr float SCALE   = 14.426950408889634f;   // 1/(EPS*ln2), EPS=0.1
constexpr float UNSCALE = 0.06931471805599453f;  // EPS*ln2
constexpr float THRESH  = 0.1f;
constexpr unsigned DUMMY_PAT = 0x7f7f7f7fu;   // memset pattern: val=3.39e38 -> exp2()==0
constexpr int RCH = 8;                        // coltop row-chunks (375 rows each)

// Sinkhorn geometry: 8 blocks/batch, wave w <-> producer-slice w (1:1)
constexpr int BPB  = 8;
constexpr int NBLK = NB * BPB;                // 64 blocks
constexpr int TPB  = 512;                     // 8 waves
constexpr int RPB  = NN / BPB;                // 375 rows per block

#if __has_builtin(__builtin_amdgcn_exp2f)
#define FEXP2(x) __builtin_amdgcn_exp2f(x)
#else
#define FEXP2(x) exp2f(x)
#endif
#if __has_builtin(__builtin_amdgcn_logf)
#define FLOG2(x) __builtin_amdgcn_logf(x)   // v_log_f32 = log2
#else
#define FLOG2(x) __log2f(x)
#endif

// Relaxed agent-scope atomics: plain coherence-point accesses, NO cache
// flushes (acquire/release at agent scope emit buffer_inv/buffer_wbl2 — the
// R2 disaster). Bypass L0/L1 — used ONLY for cross-block mutable data.
__device__ __forceinline__ float aloadf(const float* p) {
  return __hip_atomic_load(p, __ATOMIC_RELAXED, __HIP_MEMORY_SCOPE_AGENT);
}
__device__ __forceinline__ void astoref(float* p, float x) {
  __hip_atomic_store(p, x, __ATOMIC_RELAXED, __HIP_MEMORY_SCOPE_AGENT);
}
__device__ __forceinline__ int aloadi(const int* p) {
  return __hip_atomic_load(p, __ATOMIC_RELAXED, __HIP_MEMORY_SCOPE_AGENT);
}
__device__ __forceinline__ void astorei(int* p, int x) {
  __hip_atomic_store(p, x, __ATOMIC_RELAXED, __HIP_MEMORY_SCOPE_AGENT);
}

// ---------------------------------------------------------------------------
// K1: row L2 norms (as inverse) + top-8 smallest per row.
// 8 rows/block, 32 lanes/row; register top-8 + 5-round shfl_xor bitonic merge.
// ---------------------------------------------------------------------------
__global__ __launch_bounds__(256) void k_rowprep(const float* __restrict__ C,
                                                 float* __restrict__ invnorms,
                                                 int* __restrict__ rowsel) {
  const int bn = blockIdx.x * 8 + (threadIdx.x >> 5);   // row id, 8 per block
  const int l  = threadIdx.x & 31;
  const float4* row4 = reinterpret_cast<const float4*>(C + (size_t)bn * NM);

  float tv[8]; int ti[8];
#pragma unroll
  for (int q = 0; q < 8; ++q) { tv[q] = FLT_MAX; ti[q] = 0x7fffffff; }
  float sq = 0.f;
  for (int c = 0; c < 24; ++c) {              // 750 float4 / 32 lanes
    int i = l + 32 * c;
    if (i < NM / 4) {
      float4 f = row4[i];
      sq += f.x * f.x + f.y * f.y + f.z * f.z + f.w * f.w;
      float e[4] = { f.x, f.y, f.z, f.w };
#pragma unroll
      for (int j = 0; j < 4; ++j) {
        float v = e[j];
        if (v < tv[7]) {                      // stable: strict <, asc indices
          int idx = 4 * i + j;
          int pos = 8;
#pragma unroll
          for (int q = 7; q >= 0; --q) if (v < tv[q]) pos = q;
#pragma unroll
          for (int q = 7; q >= 1; --q) if (q > pos) { tv[q] = tv[q-1]; ti[q] = ti[q-1]; }
#pragma unroll
          for (int q = 0; q < 8; ++q) if (q == pos) { tv[q] = v; ti[q] = idx; }
        }
      }
    }
  }
#pragma unroll
  for (int o = 16; o; o >>= 1) sq += __shfl_down(sq, o, 32);

#pragma unroll
  for (int msk = 1; msk <= 16; msk <<= 1) {
    float pv[8]; int pi[8];
#pragma unroll
    for (int q = 0; q < 8; ++q) { pv[q] = __shfl_xor(tv[q], msk); pi[q] = __shfl_xor(ti[q], msk); }
    float mv[8]; int mi[8];
#pragma unroll
    for (int q = 0; q < 8; ++q) {             // min with reversed partner
      float av = tv[q], bv = pv[7 - q];
      int   ai = ti[q], bi = pi[7 - q];
      bool ta = (av < bv) || (av == bv && ai < bi);
      mv[q] = ta ? av : bv; mi[q] = ta ? ai : bi;
    }
    auto ce = [&](int i, int j) {             // compare-exchange (val,idx) lex
      bool sw = (mv[i] > mv[j]) || (mv[i] == mv[j] && mi[i] > mi[j]);
      float fv = sw ? mv[j] : mv[i], gv = sw ? mv[i] : mv[j];
      int   fi = sw ? mi[j] : mi[i], gi = sw ? mi[i] : mi[j];
      mv[i] = fv; mv[j] = gv; mi[i] = fi; mi[j] = gi;
    };
    ce(0,4); ce(1,5); ce(2,6); ce(3,7);       // bitonic 3-stage cleaner
    ce(0,2); ce(1,3); ce(4,6); ce(5,7);
    ce(0,1); ce(2,3); ce(4,5); ce(6,7);
#pragma unroll
    for (int q = 0; q < 8; ++q) { tv[q] = mv[q]; ti[q] = mi[q]; }
  }

  if (l == 0) {
#pragma unroll
    for (int q = 0; q < 8; ++q) rowsel[(size_t)bn * KK + q] = ti[q];
    float nm = sqrtf(sq);
    invnorms[bn] = 1.0f / fmaxf(nm, 1e-12f);
  }
}

// ---------------------------------------------------------------------------
// K2a: column top-8, phase 1. Grid (12 col-tiles, 8 row-chunks, 8 batches) =
// 768 blocks. Each block: 375 rows x 256 cols; lane owns 4 cols via float4
// (wave reads 1 KB contiguous per row); 4 waves split the 375 rows. LDS merge
// (used-mask tournament, (val desc, idx asc)) -> exact chunk top-8 per column,
// written sorted to partial[(b*RCH+rc)*NM + m][8] as int2(n, val_bits).
// ---------------------------------------------------------------------------
__global__ __launch_bounds__(256) void k_coltop1(const float* __restrict__ C,
                                                 const float* __restrict__ invnorms,
                                                 int2* __restrict__ partial) {
  const int b = blockIdx.z, rc = blockIdx.y, cg = blockIdx.x;
  const int tid = threadIdx.x;
  const int w = tid >> 6, l = tid & 63;
  const int g4 = cg * 64 + l;                 // float4 group, valid < 750
  __shared__ float sv[4][256][8];             // 32 KB
  __shared__ int   si[4][256][8];             // 32 KB

  float tv[4][8]; int ti[4][8];
#pragma unroll
  for (int j = 0; j < 4; ++j)
#pragma unroll
    for (int q = 0; q < 8; ++q) { tv[j][q] = -FLT_MAX; ti[j][q] = 0x7fffffff; }

  if (g4 < NM / 4) {
    const int base_r = rc * 375;
    const int r0 = base_r + w * 94;
    const int r1 = min(base_r + 375, r0 + 94);
    const float4* base = reinterpret_cast<const float4*>(
        C + (size_t)b * NN * NM) + g4;
    const float* ivn = invnorms + (size_t)b * NN;
    for (int n = r0; n < r1; ++n) {
      float4 f = base[(size_t)n * (NM / 4)];
      float iv = ivn[n];                      // wave-uniform -> scalar load
      float e[4] = { f.x * iv, f.y * iv, f.z * iv, f.w * iv };
#pragma unroll
      for (int j = 0; j < 4; ++j) {
        float v = e[j];
        if (v > tv[j][7]) {                   // stable: strict >, asc rows
          int pos = 8;
#pragma unroll
          for (int q = 7; q >= 0; --q) if (v > tv[j][q]) pos = q;
#pragma unroll
          for (int q = 7; q >= 1; --q) if (q > pos) { tv[j][q] = tv[j][q-1]; ti[j][q] = ti[j][q-1]; }
#pragma unroll
          for (int q = 0; q < 8; ++q) if (q == pos) { tv[j][q] = v; ti[j][q] = n; }
        }
      }
    }
  }
#pragma unroll
  for (int j = 0; j < 4; ++j)
#pragma unroll
    for (int q = 0; q < 8; ++q) { sv[w][l * 4 + j][q] = tv[j][q]; si[w][l * 4 + j][q] = ti[j][q]; }
  __syncthreads();

  int m = cg * 256 + tid;                     // one thread per tile column
  if (m < NM) {
    int2* dst = partial + (((size_t)b * RCH + rc) * NM + m) * 8;
    unsigned used = 0;
    for (int p = 0; p < KK; ++p) {
      float bv = -FLT_MAX; int bi = 0x7fffffff; int bq = 0;
#pragma unroll
      for (int c = 0; c < 4; ++c)
#pragma unroll
        for (int q = 0; q < 8; ++q) {
          int bit = c * 8 + q;
          if ((used >> bit) & 1u) continue;
          float v = sv[c][tid][q];
          int   n = si[c][tid][q];
          if (v > bv || (v == bv && n < bi)) { bv = v; bi = n; bq = bit; }
        }
      used |= 1u << bq;
      dst[p] = make_int2(bi, __float_as_int(bv));
    }
  }
}

// ---------------------------------------------------------------------------
// K2b: column top-8, phase 2. One thread per (b,m): merge 8 chunk-lists of 8
// (register-resident, fully unrolled), 64-bit used-mask tournament with
// (val desc, idx asc) — exact lax.top_k tie semantics (chunks cover disjoint
// ascending row ranges, lists exact per chunk).
// ---------------------------------------------------------------------------
__global__ __launch_bounds__(256) void k_coltop2(const int2* __restrict__ partial,
                                                 int* __restrict__ colsel) {
  int t = blockIdx.x * 256 + threadIdx.x;     // b*NM + m
  if (t >= NB * NM) return;
  int b = t / NM, m = t % NM;
  int2 cand[RCH * 8];
#pragma unroll
  for (int rc = 0; rc < RCH; ++rc) {
    const int2* src = partial + (((size_t)b * RCH + rc) * NM + m) * 8;
#pragma unroll
    for (int q = 0; q < 8; ++q) cand[rc * 8 + q] = src[q];
  }
  unsigned long long used = 0;
  for (int p = 0; p < KK; ++p) {
    float bv = -FLT_MAX; int bi = 0x7fffffff; int bq = 0;
#pragma unroll
    for (int k = 0; k < RCH * 8; ++k) {
      if ((used >> k) & 1ull) continue;
      float v = __int_as_float(cand[k].y);
      int   n = cand[k].x;
      if (v > bv || (v == bv && n < bi)) { bv = v; bi = n; bq = k; }
    }
    used |= 1ull << bq;
    colsel[(size_t)t * KK + p] = bi;
  }
}

// ---------------------------------------------------------------------------
// K3 (fused fill): base slots 0..7 of CSR/CSC + non-duplicate extras (8+).
// pk arrays pre-filled with DUMMY_PAT via hipMemsetD32Async.
// ---------------------------------------------------------------------------
__global__ __launch_bounds__(256) void k_fill(const float* __restrict__ C,
    const float* __restrict__ invnorms, const int* __restrict__ rowsel,
    const int* __restrict__ colsel, int* r_cnt, int* c_cnt,
    int2* __restrict__ r_pk, int2* __restrict__ c_pk) {
  int t = blockIdx.x * 256 + threadIdx.x;
  if (t >= NB * NN * KK) return;
  int k = t % KK; int bn = t / KK;
  int b = bn / NN; int n = bn % NN;
  {  // base row entry
    int m = rowsel[t];
    float v2 = C[((size_t)b * NN + n) * NM + m] * invnorms[bn] * SCALE;
    r_pk[(size_t)bn * CAP + k] = make_int2(m, __float_as_int(v2));
  }
  {  // base col entry (bn reinterpreted as b*NM+m)
    int m2 = n;
    int n2 = colsel[t];
    float v2 = C[((size_t)b * NN + n2) * NM + m2] * invnorms[(size_t)b * NN + n2] * SCALE;
    c_pk[(size_t)bn * CAP + k] = make_int2(n2, __float_as_int(v2));
  }
  int m = n;                                  // extras: t = (b*NM+m)*KK + k
  {  // colsel entry (b,m,k): row n3 gains column m unless duplicate
    int n3 = colsel[t];
    const int* rs = rowsel + ((size_t)b * NN + n3) * KK;
    bool dup = false;
#pragma unroll
    for (int q = 0; q < KK; ++q) dup |= (rs[q] == m);
    if (!dup) {
      int slot = 8 + atomicAdd(&r_cnt[(size_t)b * NN + n3], 1);
      if (slot < CAP) {
        float v2 = C[((size_t)b * NN + n3) * NM + m] * invnorms[(size_t)b * NN + n3] * SCALE;
        r_pk[((size_t)b * NN + n3) * CAP + slot] = make_int2(m, __float_as_int(v2));
      }
    }
  }
  {  // rowsel entry (b,n2,k): column mm gains row n2 unless duplicate
    int n2 = m;
    int mm = rowsel[t];
    const int* cs = colsel + ((size_t)b * NM + mm) * KK;
    bool dup = false;
#pragma unroll
    for (int q = 0; q < KK; ++q) dup |= (cs[q] == n2);
    if (!dup) {
      int slot = 8 + atomicAdd(&c_cnt[(size_t)b * NM + mm], 1);
      if (slot < CAP) {
        float v2 = C[((size_t)b * NN + n2) * NM + mm] * invnorms[(size_t)b * NN + n2] * SCALE;
        c_pk[((size_t)b * NM + mm) * CAP + slot] = make_int2(n2, __float_as_int(v2));
      }
    }
  }
}

// ---------------------------------------------------------------------------
// K5: pull-as-ready sparse Sinkhorn (validated R6/R7 structure, unchanged).
// ---------------------------------------------------------------------------
__global__ __launch_bounds__(TPB, 1) void k_sink_coop(
    const float* __restrict__ mu, const float* __restrict__ nu,
    const int2* __restrict__ r_pk, const int2* __restrict__ c_pk,
    float* __restrict__ Upub, float* __restrict__ Vpub,
    int* stU, int* stV, float* errW, float* __restrict__ costpart) {
  const int blk = blockIdx.x;
  const int b = blk % NB, slice = blk / NB;   // %8: batch pinned per XCD (heuristic)
  const int tid = threadIdx.x;
  const int w = tid >> 6, lane = tid & 63;
  const int r = slice * RPB + tid;
  const bool has_r = (tid < RPB);             // NN == NM: same geometry

  // wave-resident sparse entries (persistent VGPRs)
  float rval[CAP], cval[CAP];
  unsigned ridx[CAP / 2], cidx[CAP / 2];
  float u = 0.f, vv = 0.f, lmu = 0.f, lnu = 0.f;
  if (has_r) {
    const int2* rp = r_pk + ((size_t)b * NN + r) * CAP;
    const int2* cp = c_pk + ((size_t)b * NM + r) * CAP;
#pragma unroll
    for (int i = 0; i < CAP; i += 2) {
      int2 e0 = rp[i], e1 = rp[i + 1];
      rval[i] = __int_as_float(e0.y); rval[i + 1] = __int_as_float(e1.y);
      unsigned i0 = min((unsigned)e0.x & 0xFFFFu, (unsigned)(NN - 1));  // clamp dummies
      unsigned i1 = min((unsigned)e1.x & 0xFFFFu, (unsigned)(NN - 1));
      ridx[i / 2] = i0 | (i1 << 16);
      int2 f0 = cp[i], f1 = cp[i + 1];
      cval[i] = __int_as_float(f0.y); cval[i + 1] = __int_as_float(f1.y);
      unsigned j0 = min((unsigned)f0.x & 0xFFFFu, (unsigned)(NN - 1));
      unsigned j1 = min((unsigned)f1.x & 0xFFFFu, (unsigned)(NN - 1));
      cidx[i / 2] = j0 | (j1 << 16);
    }
    lmu = FLOG2(mu[(size_t)b * NN + r] + 1e-8f);
    lnu = FLOG2(nu[(size_t)b * NM + r] + 1e-8f);
  }

  __shared__ float XL[NN];                    // staged U or V (12 KB)
  __shared__ float sred[TPB / 64];
  __shared__ float errl[BPB];
  int*   stUb = stU + b * BPB * 16;
  int*   stVb = stV + b * BPB * 16;
  int itf = 0;
  bool done = false;

  for (int it = 0; it < 100; ++it) {
    // ---- stage-A: V(it-1) (zeros at it==0), wave w pulls producer w ----
    if (it == 0) {
      for (int i = tid; i < NN; i += TPB) XL[i] = 0.f;
    } else {
      const float* src = Vpub + (size_t)((it - 1) & 1) * (NB * NN) + (size_t)b * NN;
      const int* st = stVb + w * 16;
      while (aloadi(st) < it) __builtin_amdgcn_s_sleep(1);   // wave-uniform
      for (int i = lane; i < RPB; i += 64)
        XL[w * RPB + i] = aloadf(&src[w * RPB + i]);
    }
    __syncthreads();

    // ---- compute-A: u update, publish U + err ----
    float errp = 0.f;
    if (has_r) {
      float s = 0.f;
#pragma unroll
      for (int i = 0; i < CAP; ++i) {
        int ix = (ridx[i >> 1] >> ((i & 1) * 16)) & 0xFFFF;
        s += FEXP2(u + XL[ix] - rval[i]);
      }
      float un = lmu - FLOG2(1e-8f + s) + u;
      errp = fabsf(un - u);
      u = un;
      astoref(&Upub[(size_t)(it & 1) * (NB * NN) + (size_t)b * NN + r], u);
    }
#pragma unroll
    for (int o = 32; o; o >>= 1) errp += __shfl_down(errp, o);
    if (lane == 0) sred[w] = errp;
    __syncthreads();                          // drains ALL waves' U stores too
    if (tid == 0) {
      float e = sred[0] + sred[1] + sred[2] + sred[3]
              + sred[4] + sred[5] + sred[6] + sred[7];
      astoref(&errW[(size_t)((it & 1) * NB + b) * BPB * 16 + slice * 16], e);
      asm volatile("s_waitcnt vmcnt(0)" ::: "memory");
      astorei(&stUb[slice * 16], it + 1);
    }

    // ---- stage-B: U(it), wave w pulls producer w + its err word ----
    {
      const float* src = Upub + (size_t)(it & 1) * (NB * NN) + (size_t)b * NN;
      const int* st = stUb + w * 16;
      while (aloadi(st) < it + 1) __builtin_amdgcn_s_sleep(1);
      for (int i = lane; i < RPB; i += 64)
        XL[w * RPB + i] = aloadf(&src[w * RPB + i]);
      if (lane == 0)
        errl[w] = aloadf(&errW[(size_t)((it & 1) * NB + b) * BPB * 16 + w * 16]);
    }
    __syncthreads();

    // ---- compute-B: v update, publish V; uniform done decision ----
    float errtot = errl[0] + errl[1] + errl[2] + errl[3]
                 + errl[4] + errl[5] + errl[6] + errl[7];   // fixed order
    done = (errtot * UNSCALE < THRESH);
    if (has_r) {
      float s = 0.f;
#pragma unroll
      for (int i = 0; i < CAP; ++i) {
        int ix = (cidx[i >> 1] >> ((i & 1) * 16)) & 0xFFFF;
        s += FEXP2(vv + XL[ix] - cval[i]);
      }
      vv = lnu - FLOG2(1e-8f + s) + vv;
      astoref(&Vpub[(size_t)(it & 1) * (NB * NN) + (size_t)b * NN + r], vv);
    }
    __syncthreads();                          // drain all V stores
    if (tid == 0) astorei(&stVb[slice * 16], it + 1);
    itf = it;
    if (done) break;                          // uniform across the batch
  }

  // ---- epilogue: stage final V(itf), cost partial over own rows ----
  {
    const float* src = Vpub + (size_t)(itf & 1) * (NB * NN) + (size_t)b * NN;
    const int* st = stVb + w * 16;
    while (aloadi(st) < itf + 1) __builtin_amdgcn_s_sleep(1);
    for (int i = lane; i < RPB; i += 64)
      XL[w * RPB + i] = aloadf(&src[w * RPB + i]);
  }
  __syncthreads();
  float cs = 0.f;
  if (has_r) {
#pragma unroll
    for (int i = 0; i < CAP; ++i) {
      int ix = (ridx[i >> 1] >> ((i & 1) * 16)) & 0xFFFF;
      float val = rval[i];
      cs += FEXP2(u + XL[ix] - val) * val;    // dummies give exp2(-huge)*big = 0
    }
  }
#pragma unroll
  for (int o = 32; o; o >>= 1) cs += __shfl_down(cs, o);
  if (lane == 0) sred[w] = cs;
  __syncthreads();
  if (tid == 0)
    costpart[b * BPB + slice] = sred[0] + sred[1] + sred[2] + sred[3]
                              + sred[4] + sred[5] + sred[6] + sred[7];
}

// Deterministic final reduction: fixed-order sums.
__global__ void k_final2(const float* __restrict__ costpart, float* __restrict__ out) {
  if (threadIdx.x == 0 && blockIdx.x == 0) {
    float tot = 0.f;
    for (int b = 0; b < NB; ++b) {
      float cb = 0.f;
      for (int s = 0; s < BPB; ++s) cb += costpart[b * BPB + s];
      tot += cb * UNSCALE;
    }
    out[0] = tot * (1.0f / NB);
  }
}

// ---------------------------------------------------------------------------
extern "C" void kernel_launch(void* const* d_in, const int* in_sizes, int n_in,
                              void* d_out, int out_size, void* d_ws, size_t ws_size,
                              hipStream_t stream) {
  const float* mu = (const float*)d_in[0];
  const float* nu = (const float*)d_in[1];
  const float* C  = (const float*)d_in[2];
  float* out = (float*)d_out;

  char* ws = (char*)d_ws;
  size_t off = 0;
  auto alloc = [&](size_t bytes) {
    void* p = ws + off;
    off += (bytes + 255) & ~(size_t)255;
    return p;
  };
  float* invnorms = (float*)alloc(sizeof(float) * NB * NN);
  int*   rowsel   = (int*)  alloc(sizeof(int)   * NB * NN * KK);
  int*   colsel   = (int*)  alloc(sizeof(int)   * NB * NM * KK);
  int2*  partial  = (int2*) alloc(sizeof(int2)  * NB * RCH * NM * 8);  // 12.3 MB
  int2*  r_pk     = (int2*) alloc(sizeof(int2)  * NB * NN * CAP);
  int2*  c_pk     = (int2*) alloc(sizeof(int2)  * NB * NM * CAP);      // contiguous after r_pk
  float* Upub     = (float*)alloc(sizeof(float) * 2 * NB * NN);        // parity dbuf
  float* Vpub     = (float*)alloc(sizeof(float) * 2 * NB * NM);
  // ---- zeroed region starts here ----
  int*   r_cnt    = (int*)  alloc(sizeof(int)   * NB * NN);
  int*   c_cnt    = (int*)  alloc(sizeof(int)   * NB * NM);
  int*   stU      = (int*)  alloc(sizeof(int)   * NB * BPB * 16);
  int*   stV      = (int*)  alloc(sizeof(int)   * NB * BPB * 16);
  float* errW     = (float*)alloc(sizeof(float) * 2 * NB * BPB * 16);
  float* costpart = (float*)alloc(sizeof(float) * NB * BPB);
  (void)ws_size; (void)in_sizes; (void)n_in; (void)out_size;

  // pk arrays pre-filled with dummy pattern (val=3.39e38, idx clamped in sink)
  hipMemsetD32Async((hipDeviceptr_t)r_pk, (int)DUMMY_PAT,
                    (size_t)2 * NB * NN * CAP * 2, stream);
  size_t span = (size_t)((char*)costpart - (char*)r_cnt)
              + ((sizeof(float) * NB * BPB + 255) & ~(size_t)255);
  hipMemsetAsync(r_cnt, 0, span, stream);     // r_cnt..costpart (stamps -> 0)

  hipLaunchKernelGGL(k_rowprep, dim3(NB * NN / 8), dim3(256), 0, stream,
                     C, invnorms, rowsel);
  hipLaunchKernelGGL(k_coltop1, dim3(12, RCH, NB), dim3(256), 0, stream,
                     C, invnorms, partial);
  hipLaunchKernelGGL(k_coltop2, dim3((NB * NM + 255) / 256), dim3(256), 0, stream,
                     partial, colsel);
  int nthreads = NB * NN * KK;
  hipLaunchKernelGGL(k_fill, dim3((nthreads + 255) / 256), dim3(256), 0, stream,
                     C, invnorms, rowsel, colsel, r_cnt, c_cnt, r_pk, c_pk);

  void* args[] = { (void*)&mu, (void*)&nu, (void*)&r_pk, (void*)&c_pk,
                   (void*)&Upub, (void*)&Vpub, (void*)&stU, (void*)&stV,
                   (void*)&errW, (void*)&costpart };
  hipLaunchCooperativeKernel((const void*)k_sink_coop, dim3(NBLK), dim3(TPB),
                             args, 0, stream);

  hipLaunchKernelGGL(k_final2, dim3(1), dim3(64), 0, stream, costpart, out);
}

// Round 9
// 951.110 us; speedup vs baseline: 1.9055x; 1.3461x over previous
//
#include <hip/hip_runtime.h>
#include <cfloat>

typedef unsigned long long ull;

// Problem constants (match reference setup_inputs)
constexpr int NB = 8, NN = 3000, NM = 3000, KK = 8;
constexpr int CAP = 48;                       // per-row/col sparse capacity (padded)
constexpr float SCALE   = 14.426950408889634f;   // 1/(EPS*ln2), EPS=0.1
constexpr float UNSCALE = 0.06931471805599453f;  // EPS*ln2
constexpr float THRESH  = 0.1f;
constexpr unsigned DUMMY_PAT = 0x7f7f7f7fu;   // memset pattern: val=3.39e38 -> exp2()==0
constexpr int RCH = 8;                        // coltop row-chunks (375 rows each)

// Sinkhorn geometry: 8 blocks/batch, wave w <-> producer-slice w (1:1)
constexpr int BPB  = 8;
constexpr int NBLK = NB * BPB;                // 64 blocks
constexpr int TPB  = 512;                     // 8 waves
constexpr int RPB  = NN / BPB;                // 375 rows per block

#if __has_builtin(__builtin_amdgcn_exp2f)
#define FEXP2(x) __builtin_amdgcn_exp2f(x)
#else
#define FEXP2(x) exp2f(x)
#endif
#if __has_builtin(__builtin_amdgcn_logf)
#define FLOG2(x) __builtin_amdgcn_logf(x)   // v_log_f32 = log2
#else
#define FLOG2(x) __log2f(x)
#endif

// Relaxed agent-scope 64-bit atomics: plain coherence-point accesses, NO cache
// flushes (acquire/release at agent scope emit buffer_inv/buffer_wbl2 — the R2
// disaster). 64-bit units carry (tag<<32)|value so publication is in-band: no
// vmcnt drain, no separate stamp word, no stamp->data indirection RT.
__device__ __forceinline__ ull aload64(const ull* p) {
  return __hip_atomic_load(p, __ATOMIC_RELAXED, __HIP_MEMORY_SCOPE_AGENT);
}
__device__ __forceinline__ void astore64(ull* p, ull x) {
  __hip_atomic_store(p, x, __ATOMIC_RELAXED, __HIP_MEMORY_SCOPE_AGENT);
}

// Pull one producer slice (RPB=375 tagged ulls) into LDS. Batched first
// attempt (6 independent loads pipeline in one MALL latency window), then
// re-poll stragglers only.
__device__ __forceinline__ void pull_tagged(const ull* __restrict__ src, int tag,
                                            float* __restrict__ dst, int lane) {
  const int nfull = RPB - 5 * 64;             // 55: lanes < 55 own 6 elements
  unsigned pend = (lane < nfull) ? 0x3Fu : 0x1Fu;
  {
    ull x0 = aload64(&src[lane]);
    ull x1 = aload64(&src[lane + 64]);
    ull x2 = aload64(&src[lane + 128]);
    ull x3 = aload64(&src[lane + 192]);
    ull x4 = aload64(&src[lane + 256]);
    ull x5 = (lane < nfull) ? aload64(&src[lane + 320]) : 0;
    if ((int)(x0 >> 32) == tag) { dst[lane]       = __uint_as_float((unsigned)x0); pend &= ~1u;  }
    if ((int)(x1 >> 32) == tag) { dst[lane + 64]  = __uint_as_float((unsigned)x1); pend &= ~2u;  }
    if ((int)(x2 >> 32) == tag) { dst[lane + 128] = __uint_as_float((unsigned)x2); pend &= ~4u;  }
    if ((int)(x3 >> 32) == tag) { dst[lane + 192] = __uint_as_float((unsigned)x3); pend &= ~8u;  }
    if ((int)(x4 >> 32) == tag) { dst[lane + 256] = __uint_as_float((unsigned)x4); pend &= ~16u; }
    if ((lane < nfull) && (int)(x5 >> 32) == tag) { dst[lane + 320] = __uint_as_float((unsigned)x5); pend &= ~32u; }
  }
  while (pend) {
    __builtin_amdgcn_s_sleep(1);
#pragma unroll
    for (int j = 0; j < 6; ++j) {
      if (!((pend >> j) & 1u)) continue;
      ull x = aload64(&src[lane + 64 * j]);
      if ((int)(x >> 32) == tag) {
        dst[lane + 64 * j] = __uint_as_float((unsigned)x);
        pend &= ~(1u << j);
      }
    }
  }
}

// ---------------------------------------------------------------------------
// K1: row L2 norms (as inverse) + top-8 smallest per row.
// 8 rows/block, 32 lanes/row; register top-8 + 5-round shfl_xor bitonic merge.
// ---------------------------------------------------------------------------
__global__ __launch_bounds__(256) void k_rowprep(const float* __restrict__ C,
                                                 float* __restrict__ invnorms,
                                                 int* __restrict__ rowsel) {
  const int bn = blockIdx.x * 8 + (threadIdx.x >> 5);   // row id, 8 per block
  const int l  = threadIdx.x & 31;
  const float4* row4 = reinterpret_cast<const float4*>(C + (size_t)bn * NM);

  float tv[8]; int ti[8];
#pragma unroll
  for (int q = 0; q < 8; ++q) { tv[q] = FLT_MAX; ti[q] = 0x7fffffff; }
  float sq = 0.f;
  for (int c = 0; c < 24; ++c) {              // 750 float4 / 32 lanes
    int i = l + 32 * c;
    if (i < NM / 4) {
      float4 f = row4[i];
      sq += f.x * f.x + f.y * f.y + f.z * f.z + f.w * f.w;
      float e[4] = { f.x, f.y, f.z, f.w };
#pragma unroll
      for (int j = 0; j < 4; ++j) {
        float v = e[j];
        if (v < tv[7]) {                      // stable: strict <, asc indices
          int idx = 4 * i + j;
          int pos = 8;
#pragma unroll
          for (int q = 7; q >= 0; --q) if (v < tv[q]) pos = q;
#pragma unroll
          for (int q = 7; q >= 1; --q) if (q > pos) { tv[q] = tv[q-1]; ti[q] = ti[q-1]; }
#pragma unroll
          for (int q = 0; q < 8; ++q) if (q == pos) { tv[q] = v; ti[q] = idx; }
        }
      }
    }
  }
#pragma unroll
  for (int o = 16; o; o >>= 1) sq += __shfl_down(sq, o, 32);

#pragma unroll
  for (int msk = 1; msk <= 16; msk <<= 1) {
    float pv[8]; int pi[8];
#pragma unroll
    for (int q = 0; q < 8; ++q) { pv[q] = __shfl_xor(tv[q], msk); pi[q] = __shfl_xor(ti[q], msk); }
    float mv[8]; int mi[8];
#pragma unroll
    for (int q = 0; q < 8; ++q) {             // min with reversed partner
      float av = tv[q], bv = pv[7 - q];
      int   ai = ti[q], bi = pi[7 - q];
      bool ta = (av < bv) || (av == bv && ai < bi);
      mv[q] = ta ? av : bv; mi[q] = ta ? ai : bi;
    }
    auto ce = [&](int i, int j) {             // compare-exchange (val,idx) lex
      bool sw = (mv[i] > mv[j]) || (mv[i] == mv[j] && mi[i] > mi[j]);
      float fv = sw ? mv[j] : mv[i], gv = sw ? mv[i] : mv[j];
      int   fi = sw ? mi[j] : mi[i], gi = sw ? mi[i] : mi[j];
      mv[i] = fv; mv[j] = gv; mi[i] = fi; mi[j] = gi;
    };
    ce(0,4); ce(1,5); ce(2,6); ce(3,7);       // bitonic 3-stage cleaner
    ce(0,2); ce(1,3); ce(4,6); ce(5,7);
    ce(0,1); ce(2,3); ce(4,5); ce(6,7);
#pragma unroll
    for (int q = 0; q < 8; ++q) { tv[q] = mv[q]; ti[q] = mi[q]; }
  }

  if (l == 0) {
#pragma unroll
    for (int q = 0; q < 8; ++q) rowsel[(size_t)bn * KK + q] = ti[q];
    float nm = sqrtf(sq);
    invnorms[bn] = 1.0f / fmaxf(nm, 1e-12f);
  }
}

// ---------------------------------------------------------------------------
// K2a: column top-8, phase 1 (768 blocks; exact chunk top-8 per column).
// ---------------------------------------------------------------------------
__global__ __launch_bounds__(256) void k_coltop1(const float* __restrict__ C,
                                                 const float* __restrict__ invnorms,
                                                 int2* __restrict__ partial) {
  const int b = blockIdx.z, rc = blockIdx.y, cg = blockIdx.x;
  const int tid = threadIdx.x;
  const int w = tid >> 6, l = tid & 63;
  const int g4 = cg * 64 + l;                 // float4 group, valid < 750
  __shared__ float sv[4][256][8];             // 32 KB
  __shared__ int   si[4][256][8];             // 32 KB

  float tv[4][8]; int ti[4][8];
#pragma unroll
  for (int j = 0; j < 4; ++j)
#pragma unroll
    for (int q = 0; q < 8; ++q) { tv[j][q] = -FLT_MAX; ti[j][q] = 0x7fffffff; }

  if (g4 < NM / 4) {
    const int base_r = rc * 375;
    const int r0 = base_r + w * 94;
    const int r1 = min(base_r + 375, r0 + 94);
    const float4* base = reinterpret_cast<const float4*>(
        C + (size_t)b * NN * NM) + g4;
    const float* ivn = invnorms + (size_t)b * NN;
    for (int n = r0; n < r1; ++n) {
      float4 f = base[(size_t)n * (NM / 4)];
      float iv = ivn[n];                      // wave-uniform -> scalar load
      float e[4] = { f.x * iv, f.y * iv, f.z * iv, f.w * iv };
#pragma unroll
      for (int j = 0; j < 4; ++j) {
        float v = e[j];
        if (v > tv[j][7]) {                   // stable: strict >, asc rows
          int pos = 8;
#pragma unroll
          for (int q = 7; q >= 0; --q) if (v > tv[j][q]) pos = q;
#pragma unroll
          for (int q = 7; q >= 1; --q) if (q > pos) { tv[j][q] = tv[j][q-1]; ti[j][q] = ti[j][q-1]; }
#pragma unroll
          for (int q = 0; q < 8; ++q) if (q == pos) { tv[j][q] = v; ti[j][q] = n; }
        }
      }
    }
  }
#pragma unroll
  for (int j = 0; j < 4; ++j)
#pragma unroll
    for (int q = 0; q < 8; ++q) { sv[w][l * 4 + j][q] = tv[j][q]; si[w][l * 4 + j][q] = ti[j][q]; }
  __syncthreads();

  int m = cg * 256 + tid;                     // one thread per tile column
  if (m < NM) {
    int2* dst = partial + (((size_t)b * RCH + rc) * NM + m) * 8;
    unsigned used = 0;
    for (int p = 0; p < KK; ++p) {
      float bv = -FLT_MAX; int bi = 0x7fffffff; int bq = 0;
      for (int c = 0; c < 4; ++c)
        for (int q = 0; q < 8; ++q) {
          int bit = c * 8 + q;
          if ((used >> bit) & 1u) continue;
          float v = sv[c][tid][q];
          int   n = si[c][tid][q];
          if (v > bv || (v == bv && n < bi)) { bv = v; bi = n; bq = bit; }
        }
      used |= 1u << bq;
      dst[p] = make_int2(bi, __float_as_int(bv));
    }
  }
}

// ---------------------------------------------------------------------------
// K2b: column top-8, phase 2 (register-resident merge of 8 sorted chunk-lists;
// runtime loops to keep compile time sane).
// ---------------------------------------------------------------------------
__global__ __launch_bounds__(256) void k_coltop2(const int2* __restrict__ partial,
                                                 int* __restrict__ colsel) {
  int t = blockIdx.x * 256 + threadIdx.x;     // b*NM + m
  if (t >= NB * NM) return;
  int b = t / NM, m = t % NM;
  int2 cand[RCH * 8];
  for (int rc = 0; rc < RCH; ++rc) {
    const int2* src = partial + (((size_t)b * RCH + rc) * NM + m) * 8;
    for (int q = 0; q < 8; ++q) cand[rc * 8 + q] = src[q];
  }
  ull used = 0;
  for (int p = 0; p < KK; ++p) {
    float bv = -FLT_MAX; int bi = 0x7fffffff; int bq = 0;
    for (int k = 0; k < RCH * 8; ++k) {
      if ((used >> k) & 1ull) continue;
      float v = __int_as_float(cand[k].y);
      int   n = cand[k].x;
      if (v > bv || (v == bv && n < bi)) { bv = v; bi = n; bq = k; }
    }
    used |= 1ull << bq;
    colsel[(size_t)t * KK + p] = bi;
  }
}

// ---------------------------------------------------------------------------
// K3 (fused fill): base slots 0..7 of CSR/CSC + non-duplicate extras (8+).
// pk arrays pre-filled with DUMMY_PAT via hipMemsetD32Async.
// ---------------------------------------------------------------------------
__global__ __launch_bounds__(256) void k_fill(const float* __restrict__ C,
    const float* __restrict__ invnorms, const int* __restrict__ rowsel,
    const int* __restrict__ colsel, int* r_cnt, int* c_cnt,
    int2* __restrict__ r_pk, int2* __restrict__ c_pk) {
  int t = blockIdx.x * 256 + threadIdx.x;
  if (t >= NB * NN * KK) return;
  int k = t % KK; int bn = t / KK;
  int b = bn / NN; int n = bn % NN;
  {  // base row entry
    int m = rowsel[t];
    float v2 = C[((size_t)b * NN + n) * NM + m] * invnorms[bn] * SCALE;
    r_pk[(size_t)bn * CAP + k] = make_int2(m, __float_as_int(v2));
  }
  {  // base col entry (bn reinterpreted as b*NM+m)
    int m2 = n;
    int n2 = colsel[t];
    float v2 = C[((size_t)b * NN + n2) * NM + m2] * invnorms[(size_t)b * NN + n2] * SCALE;
    c_pk[(size_t)bn * CAP + k] = make_int2(n2, __float_as_int(v2));
  }
  int m = n;                                  // extras: t = (b*NM+m)*KK + k
  {  // colsel entry (b,m,k): row n3 gains column m unless duplicate
    int n3 = colsel[t];
    const int* rs = rowsel + ((size_t)b * NN + n3) * KK;
    bool dup = false;
#pragma unroll
    for (int q = 0; q < KK; ++q) dup |= (rs[q] == m);
    if (!dup) {
      int slot = 8 + atomicAdd(&r_cnt[(size_t)b * NN + n3], 1);
      if (slot < CAP) {
        float v2 = C[((size_t)b * NN + n3) * NM + m] * invnorms[(size_t)b * NN + n3] * SCALE;
        r_pk[((size_t)b * NN + n3) * CAP + slot] = make_int2(m, __float_as_int(v2));
      }
    }
  }
  {  // rowsel entry (b,n2,k): column mm gains row n2 unless duplicate
    int n2 = m;
    int mm = rowsel[t];
    const int* cs = colsel + ((size_t)b * NM + mm) * KK;
    bool dup = false;
#pragma unroll
    for (int q = 0; q < KK; ++q) dup |= (cs[q] == n2);
    if (!dup) {
      int slot = 8 + atomicAdd(&c_cnt[(size_t)b * NM + mm], 1);
      if (slot < CAP) {
        float v2 = C[((size_t)b * NN + n2) * NM + mm] * invnorms[(size_t)b * NN + n2] * SCALE;
        c_pk[((size_t)b * NM + mm) * CAP + slot] = make_int2(n2, __float_as_int(v2));
      }
    }
  }
}

// ---------------------------------------------------------------------------
// K5: tagged pull-as-ready sparse Sinkhorn. 8 blocks/batch. Values published
// as (tag<<32)|bits via relaxed 64-bit agent atomics into parity buffers;
// consumers poll the data itself. Own slice goes registers->LDS (no MALL RT).
// Reuse-distance-2: a producer reaches A(it+2) only after every block consumed
// U(it)/V(it)/err(it), so pollers can only ever see stale tags, never future
// ones. All blocks of a batch compute the identical fixed-order err sum ->
// uniform deterministic break (reference freeze semantics preserved).
// ---------------------------------------------------------------------------
__global__ __launch_bounds__(TPB, 1) void k_sink_coop(
    const float* __restrict__ mu, const float* __restrict__ nu,
    const int2* __restrict__ r_pk, const int2* __restrict__ c_pk,
    ull* __restrict__ Upub, ull* __restrict__ Vpub,
    ull* errW, float* __restrict__ costpart) {
  const int blk = blockIdx.x;
  const int b = blk % NB, slice = blk / NB;   // %8: batch spread over XCDs (heuristic)
  const int tid = threadIdx.x;
  const int w = tid >> 6, lane = tid & 63;
  const int r = slice * RPB + tid;
  const bool has_r = (tid < RPB);             // NN == NM: same geometry

  // wave-resident sparse entries (persistent VGPRs)
  float rval[CAP], cval[CAP];
  unsigned ridx[CAP / 2], cidx[CAP / 2];
  float u = 0.f, vv = 0.f, lmu = 0.f, lnu = 0.f;
  if (has_r) {
    const int2* rp = r_pk + ((size_t)b * NN + r) * CAP;
    const int2* cp = c_pk + ((size_t)b * NM + r) * CAP;
#pragma unroll
    for (int i = 0; i < CAP; i += 2) {
      int2 e0 = rp[i], e1 = rp[i + 1];
      rval[i] = __int_as_float(e0.y); rval[i + 1] = __int_as_float(e1.y);
      unsigned i0 = min((unsigned)e0.x & 0xFFFFu, (unsigned)(NN - 1));  // clamp dummies
      unsigned i1 = min((unsigned)e1.x & 0xFFFFu, (unsigned)(NN - 1));
      ridx[i / 2] = i0 | (i1 << 16);
      int2 f0 = cp[i], f1 = cp[i + 1];
      cval[i] = __int_as_float(f0.y); cval[i + 1] = __int_as_float(f1.y);
      unsigned j0 = min((unsigned)f0.x & 0xFFFFu, (unsigned)(NN - 1));
      unsigned j1 = min((unsigned)f1.x & 0xFFFFu, (unsigned)(NN - 1));
      cidx[i / 2] = j0 | (j1 << 16);
    }
    lmu = FLOG2(mu[(size_t)b * NN + r] + 1e-8f);
    lnu = FLOG2(nu[(size_t)b * NM + r] + 1e-8f);
  }

  __shared__ float XL[NN];                    // staged U or V (12 KB)
  __shared__ float sred[TPB / 64];
  __shared__ float errl[BPB];
  int itf = 0;
  bool done = false;

  for (int it = 0; it < 100; ++it) {
    // ---- stage-A: XL <- V(it-1) (zeros at it==0); own slice from registers ----
    if (it == 0) {
      for (int i = tid; i < NN; i += TPB) XL[i] = 0.f;
    } else {
      if (has_r) XL[r] = vv;
      if (w != slice) {
        const ull* src = Vpub + (size_t)((it - 1) & 1) * (NB * NN)
                       + (size_t)b * NN + (size_t)w * RPB;
        pull_tagged(src, it, XL + w * RPB, lane);
      }
    }
    __syncthreads();

    // ---- compute-A: u update, publish tagged U ----
    float errp = 0.f;
    if (has_r) {
      float s = 0.f;
#pragma unroll
      for (int i = 0; i < CAP; ++i) {
        int ix = (ridx[i >> 1] >> ((i & 1) * 16)) & 0xFFFF;
        s += FEXP2(u + XL[ix] - rval[i]);
      }
      float un = lmu - FLOG2(1e-8f + s) + u;
      errp = fabsf(un - u);
      u = un;
      astore64(&Upub[(size_t)(it & 1) * (NB * NN) + (size_t)b * NN + r],
               ((ull)(unsigned)(it + 1) << 32) | __float_as_uint(u));
    }
#pragma unroll
    for (int o = 32; o; o >>= 1) errp += __shfl_down(errp, o);
    if (lane == 0) sred[w] = errp;
    __syncthreads();                          // also: XL(V) reads done -> safe to overwrite
    if (tid == 0) {
      float e = sred[0] + sred[1] + sred[2] + sred[3]
              + sred[4] + sred[5] + sred[6] + sred[7];
      astore64(&errW[(size_t)((it & 1) * NB + b) * BPB * 16 + slice * 16],
               ((ull)(unsigned)(it + 1) << 32) | __float_as_uint(e));
      errl[slice] = e;
    }

    // ---- stage-B: XL <- U(it); own slice from registers; err words ----
    if (has_r) XL[r] = u;
    if (w != slice) {
      const ull* src = Upub + (size_t)(it & 1) * (NB * NN)
                     + (size_t)b * NN + (size_t)w * RPB;
      pull_tagged(src, it + 1, XL + w * RPB, lane);
      if (lane == 0) {
        const ull* ep = errW + (size_t)((it & 1) * NB + b) * BPB * 16 + w * 16;
        ull x = aload64(ep);
        while ((int)(x >> 32) != it + 1) { __builtin_amdgcn_s_sleep(1); x = aload64(ep); }
        errl[w] = __uint_as_float((unsigned)x);
      }
    }
    __syncthreads();

    // ---- compute-B: uniform done decision, v update, publish tagged V ----
    float errtot = errl[0] + errl[1] + errl[2] + errl[3]
                 + errl[4] + errl[5] + errl[6] + errl[7];   // fixed order
    done = (errtot * UNSCALE < THRESH);
    if (has_r) {
      float s = 0.f;
#pragma unroll
      for (int i = 0; i < CAP; ++i) {
        int ix = (cidx[i >> 1] >> ((i & 1) * 16)) & 0xFFFF;
        s += FEXP2(vv + XL[ix] - cval[i]);
      }
      vv = lnu - FLOG2(1e-8f + s) + vv;
      astore64(&Vpub[(size_t)(it & 1) * (NB * NN) + (size_t)b * NN + r],
               ((ull)(unsigned)(it + 1) << 32) | __float_as_uint(vv));
    }
    __syncthreads();                          // XL(U) reads done -> next overwrite safe
    itf = it;
    if (done) break;                          // uniform across the batch
  }

  // ---- epilogue: XL <- V(itf); cost partial over own rows ----
  if (has_r) XL[r] = vv;
  if (w != slice) {
    const ull* src = Vpub + (size_t)(itf & 1) * (NB * NN)
                   + (size_t)b * NN + (size_t)w * RPB;
    pull_tagged(src, itf + 1, XL + w * RPB, lane);
  }
  __syncthreads();
  float cs = 0.f;
  if (has_r) {
#pragma unroll
    for (int i = 0; i < CAP; ++i) {
      int ix = (ridx[i >> 1] >> ((i & 1) * 16)) & 0xFFFF;
      float val = rval[i];
      cs += FEXP2(u + XL[ix] - val) * val;    // dummies give exp2(-huge)*big = 0
    }
  }
#pragma unroll
  for (int o = 32; o; o >>= 1) cs += __shfl_down(cs, o);
  if (lane == 0) sred[w] = cs;
  __syncthreads();
  if (tid == 0)
    costpart[b * BPB + slice] = sred[0] + sred[1] + sred[2] + sred[3]
                              + sred[4] + sred[5] + sred[6] + sred[7];
}

// Deterministic final reduction: fixed-order sums.
__global__ void k_final2(const float* __restrict__ costpart, float* __restrict__ out) {
  if (threadIdx.x == 0 && blockIdx.x == 0) {
    float tot = 0.f;
    for (int b = 0; b < NB; ++b) {
      float cb = 0.f;
      for (int s = 0; s < BPB; ++s) cb += costpart[b * BPB + s];
      tot += cb * UNSCALE;
    }
    out[0] = tot * (1.0f / NB);
  }
}

// ---------------------------------------------------------------------------
extern "C" void kernel_launch(void* const* d_in, const int* in_sizes, int n_in,
                              void* d_out, int out_size, void* d_ws, size_t ws_size,
                              hipStream_t stream) {
  const float* mu = (const float*)d_in[0];
  const float* nu = (const float*)d_in[1];
  const float* C  = (const float*)d_in[2];
  float* out = (float*)d_out;

  char* ws = (char*)d_ws;
  size_t off = 0;
  auto alloc = [&](size_t bytes) {
    void* p = ws + off;
    off += (bytes + 255) & ~(size_t)255;
    return p;
  };
  float* invnorms = (float*)alloc(sizeof(float) * NB * NN);
  int*   rowsel   = (int*)  alloc(sizeof(int)   * NB * NN * KK);
  int*   colsel   = (int*)  alloc(sizeof(int)   * NB * NM * KK);
  int2*  partial  = (int2*) alloc(sizeof(int2)  * NB * RCH * NM * 8);  // 12.3 MB
  int2*  r_pk     = (int2*) alloc(sizeof(int2)  * NB * NN * CAP);
  int2*  c_pk     = (int2*) alloc(sizeof(int2)  * NB * NM * CAP);      // contiguous after r_pk
  // ---- zeroed region starts here (tags must reset every launch/replay) ----
  ull*   Upub     = (ull*)  alloc(sizeof(ull)   * 2 * NB * NN);        // tagged parity dbuf
  ull*   Vpub     = (ull*)  alloc(sizeof(ull)   * 2 * NB * NM);
  ull*   errW     = (ull*)  alloc(sizeof(ull)   * 2 * NB * BPB * 16);
  int*   r_cnt    = (int*)  alloc(sizeof(int)   * NB * NN);
  int*   c_cnt    = (int*)  alloc(sizeof(int)   * NB * NM);
  float* costpart = (float*)alloc(sizeof(float) * NB * BPB);
  (void)ws_size; (void)in_sizes; (void)n_in; (void)out_size;

  // pk arrays pre-filled with dummy pattern (val=3.39e38, idx clamped in sink)
  hipMemsetD32Async((hipDeviceptr_t)r_pk, (int)DUMMY_PAT,
                    (size_t)2 * NB * NN * CAP * 2, stream);
  size_t span = (size_t)((char*)costpart - (char*)Upub)
              + ((sizeof(float) * NB * BPB + 255) & ~(size_t)255);
  hipMemsetAsync(Upub, 0, span, stream);      // Upub..costpart (tags -> 0)

  hipLaunchKernelGGL(k_rowprep, dim3(NB * NN / 8), dim3(256), 0, stream,
                     C, invnorms, rowsel);
  hipLaunchKernelGGL(k_coltop1, dim3(12, RCH, NB), dim3(256), 0, stream,
                     C, invnorms, partial);
  hipLaunchKernelGGL(k_coltop2, dim3((NB * NM + 255) / 256), dim3(256), 0, stream,
                     partial, colsel);
  int nthreads = NB * NN * KK;
  hipLaunchKernelGGL(k_fill, dim3((nthreads + 255) / 256), dim3(256), 0, stream,
                     C, invnorms, rowsel, colsel, r_cnt, c_cnt, r_pk, c_pk);

  void* args[] = { (void*)&mu, (void*)&nu, (void*)&r_pk, (void*)&c_pk,
                   (void*)&Upub, (void*)&Vpub, (void*)&errW, (void*)&costpart };
  hipLaunchCooperativeKernel((const void*)k_sink_coop, dim3(NBLK), dim3(TPB),
                             args, 0, stream);

  hipLaunchKernelGGL(k_final2, dim3(1), dim3(64), 0, stream, costpart, out);
}

// Round 10
// 831.919 us; speedup vs baseline: 2.1786x; 1.1433x over previous
//
#include <hip/hip_runtime.h>
#include <cfloat>

typedef unsigned long long ull;

// Problem constants (match reference setup_inputs)
constexpr int NB = 8, NN = 3000, NM = 3000, KK = 8;
constexpr int CAP = 48;                       // per-row/col sparse capacity (padded)
constexpr float SCALE   = 14.426950408889634f;   // 1/(EPS*ln2), EPS=0.1
constexpr float UNSCALE = 0.06931471805599453f;  // EPS*ln2
constexpr float THRESH  = 0.1f;
constexpr unsigned DUMMY_PAT = 0x7f7f7f7fu;   // memset pattern: val=3.39e38 -> exp2()==0
constexpr int NCH = 32;                       // coltop chunks (94/93 rows each)

// Sinkhorn geometry: 8 blocks/batch, wave w <-> producer-slice w (1:1)
constexpr int BPB  = 8;
constexpr int NBLK = NB * BPB;                // 64 blocks
constexpr int TPB  = 512;                     // 8 waves
constexpr int RPB  = NN / BPB;                // 375 rows per block

#if __has_builtin(__builtin_amdgcn_exp2f)
#define FEXP2(x) __builtin_amdgcn_exp2f(x)
#else
#define FEXP2(x) exp2f(x)
#endif
#if __has_builtin(__builtin_amdgcn_logf)
#define FLOG2(x) __builtin_amdgcn_logf(x)   // v_log_f32 = log2
#else
#define FLOG2(x) __log2f(x)
#endif

// Relaxed agent-scope 64-bit atomics: plain coherence-point accesses, NO cache
// flushes (acquire/release at agent scope emit buffer_inv/buffer_wbl2 — the R2
// disaster). 64-bit units carry (tag<<32)|value so publication is in-band.
__device__ __forceinline__ ull aload64(const ull* p) {
  return __hip_atomic_load(p, __ATOMIC_RELAXED, __HIP_MEMORY_SCOPE_AGENT);
}
__device__ __forceinline__ void astore64(ull* p, ull x) {
  __hip_atomic_store(p, x, __ATOMIC_RELAXED, __HIP_MEMORY_SCOPE_AGENT);
}

// Pull one producer slice (RPB=375 tagged ulls) into LDS. Batched first
// attempt (6 independent loads in one MALL latency window), re-poll stragglers.
__device__ __forceinline__ void pull_tagged(const ull* __restrict__ src, int tag,
                                            float* __restrict__ dst, int lane) {
  const int nfull = RPB - 5 * 64;             // 55: lanes < 55 own 6 elements
  unsigned pend = (lane < nfull) ? 0x3Fu : 0x1Fu;
  {
    ull x0 = aload64(&src[lane]);
    ull x1 = aload64(&src[lane + 64]);
    ull x2 = aload64(&src[lane + 128]);
    ull x3 = aload64(&src[lane + 192]);
    ull x4 = aload64(&src[lane + 256]);
    ull x5 = (lane < nfull) ? aload64(&src[lane + 320]) : 0;
    if ((int)(x0 >> 32) == tag) { dst[lane]       = __uint_as_float((unsigned)x0); pend &= ~1u;  }
    if ((int)(x1 >> 32) == tag) { dst[lane + 64]  = __uint_as_float((unsigned)x1); pend &= ~2u;  }
    if ((int)(x2 >> 32) == tag) { dst[lane + 128] = __uint_as_float((unsigned)x2); pend &= ~4u;  }
    if ((int)(x3 >> 32) == tag) { dst[lane + 192] = __uint_as_float((unsigned)x3); pend &= ~8u;  }
    if ((int)(x4 >> 32) == tag) { dst[lane + 256] = __uint_as_float((unsigned)x4); pend &= ~16u; }
    if ((lane < nfull) && (int)(x5 >> 32) == tag) { dst[lane + 320] = __uint_as_float((unsigned)x5); pend &= ~32u; }
  }
  while (pend) {
    __builtin_amdgcn_s_sleep(1);
#pragma unroll
    for (int j = 0; j < 6; ++j) {
      if (!((pend >> j) & 1u)) continue;
      ull x = aload64(&src[lane + 64 * j]);
      if ((int)(x >> 32) == tag) {
        dst[lane + 64 * j] = __uint_as_float((unsigned)x);
        pend &= ~(1u << j);
      }
    }
  }
}

// ---------------------------------------------------------------------------
// K1: row L2 norms (as inverse) + top-8 smallest per row, VALUES kept.
// 8 rows/block, 32 lanes/row; register top-8 + 5-round shfl_xor bitonic merge.
// rowsel[t] = int2(m, raw C bits)  -> fill never re-reads C.
// ---------------------------------------------------------------------------
__global__ __launch_bounds__(256) void k_rowprep(const float* __restrict__ C,
                                                 float* __restrict__ invnorms,
                                                 int2* __restrict__ rowsel) {
  const int bn = blockIdx.x * 8 + (threadIdx.x >> 5);   // row id, 8 per block
  const int l  = threadIdx.x & 31;
  const float4* row4 = reinterpret_cast<const float4*>(C + (size_t)bn * NM);

  float tv[8]; int ti[8];
#pragma unroll
  for (int q = 0; q < 8; ++q) { tv[q] = FLT_MAX; ti[q] = 0x7fffffff; }
  float sq = 0.f;
  for (int c = 0; c < 24; ++c) {              // 750 float4 / 32 lanes
    int i = l + 32 * c;
    if (i < NM / 4) {
      float4 f = row4[i];
      sq += f.x * f.x + f.y * f.y + f.z * f.z + f.w * f.w;
      float e[4] = { f.x, f.y, f.z, f.w };
#pragma unroll
      for (int j = 0; j < 4; ++j) {
        float v = e[j];
        if (v < tv[7]) {                      // stable: strict <, asc indices
          int idx = 4 * i + j;
          int pos = 8;
#pragma unroll
          for (int q = 7; q >= 0; --q) if (v < tv[q]) pos = q;
#pragma unroll
          for (int q = 7; q >= 1; --q) if (q > pos) { tv[q] = tv[q-1]; ti[q] = ti[q-1]; }
#pragma unroll
          for (int q = 0; q < 8; ++q) if (q == pos) { tv[q] = v; ti[q] = idx; }
        }
      }
    }
  }
#pragma unroll
  for (int o = 16; o; o >>= 1) sq += __shfl_down(sq, o, 32);

#pragma unroll
  for (int msk = 1; msk <= 16; msk <<= 1) {
    float pv[8]; int pi[8];
#pragma unroll
    for (int q = 0; q < 8; ++q) { pv[q] = __shfl_xor(tv[q], msk); pi[q] = __shfl_xor(ti[q], msk); }
    float mv[8]; int mi[8];
#pragma unroll
    for (int q = 0; q < 8; ++q) {             // min with reversed partner
      float av = tv[q], bv = pv[7 - q];
      int   ai = ti[q], bi = pi[7 - q];
      bool ta = (av < bv) || (av == bv && ai < bi);
      mv[q] = ta ? av : bv; mi[q] = ta ? ai : bi;
    }
    auto ce = [&](int i, int j) {             // compare-exchange (val,idx) lex
      bool sw = (mv[i] > mv[j]) || (mv[i] == mv[j] && mi[i] > mi[j]);
      float fv = sw ? mv[j] : mv[i], gv = sw ? mv[i] : mv[j];
      int   fi = sw ? mi[j] : mi[i], gi = sw ? mi[i] : mi[j];
      mv[i] = fv; mv[j] = gv; mi[i] = fi; mi[j] = gi;
    };
    ce(0,4); ce(1,5); ce(2,6); ce(3,7);       // bitonic 3-stage cleaner
    ce(0,2); ce(1,3); ce(4,6); ce(5,7);
    ce(0,1); ce(2,3); ce(4,5); ce(6,7);
#pragma unroll
    for (int q = 0; q < 8; ++q) { tv[q] = mv[q]; ti[q] = mi[q]; }
  }

  if (l == 0) {
#pragma unroll
    for (int q = 0; q < 8; ++q)
      rowsel[(size_t)bn * KK + q] = make_int2(ti[q], __float_as_int(tv[q]));
    float nm = sqrtf(sq);
    invnorms[bn] = 1.0f / fmaxf(nm, 1e-12f);
  }
}

// ---------------------------------------------------------------------------
// K2a: column top-8, phase 1. NO LDS, no syncthreads: each wave owns one
// ~94-row chunk; lane owns 4 columns via float4 (1 KB/row/wave contiguous).
// Candidates packed as key = (valbits<<32) | ~n : single u64 compare gives
// exact (val desc, n asc) lax.top_k order (vals >= 0, n distinct). Each wave
// writes its sorted 8-list per column straight to partial (lane: 256 B contig).
// ---------------------------------------------------------------------------
__global__ __launch_bounds__(256) void k_coltop1(const float* __restrict__ C,
                                                 const float* __restrict__ invnorms,
                                                 ull* __restrict__ partial) {
  const int b = blockIdx.z, rc = blockIdx.y, cg = blockIdx.x;
  const int tid = threadIdx.x;
  const int w = tid >> 6, l = tid & 63;
  const int g4 = cg * 64 + l;                 // float4 group, valid < 750
  const int chunk = rc * 4 + w;               // 0..31

  ull tv[4][8];
#pragma unroll
  for (int j = 0; j < 4; ++j)
#pragma unroll
    for (int q = 0; q < 8; ++q) tv[j][q] = 0;   // real keys always > 0

  if (g4 < NM / 4) {
    const int base_r = rc * 375;
    const int r0 = base_r + w * 94;
    const int r1 = min(base_r + 375, r0 + 94);
    const float4* base = reinterpret_cast<const float4*>(
        C + (size_t)b * NN * NM) + g4;
    const float* ivn = invnorms + (size_t)b * NN;
    for (int n = r0; n < r1; ++n) {
      float4 f = base[(size_t)n * (NM / 4)];
      float iv = ivn[n];                      // wave-uniform -> scalar load
      float e[4] = { f.x * iv, f.y * iv, f.z * iv, f.w * iv };
      ull lo = (ull)(unsigned)~n;
#pragma unroll
      for (int j = 0; j < 4; ++j) {
        ull key = ((ull)__float_as_uint(e[j]) << 32) | lo;
        if (key > tv[j][7]) {
          int pos = 8;
#pragma unroll
          for (int q = 7; q >= 0; --q) if (key > tv[j][q]) pos = q;
#pragma unroll
          for (int q = 7; q >= 1; --q) if (q > pos) tv[j][q] = tv[j][q-1];
#pragma unroll
          for (int q = 0; q < 8; ++q) if (q == pos) tv[j][q] = key;
        }
      }
    }
    ull* dst = partial + (((size_t)b * NCH + chunk) * NM + (size_t)4 * g4) * 8;
#pragma unroll
    for (int j = 0; j < 4; ++j)
#pragma unroll
      for (int q = 0; q < 8; ++q) dst[j * 8 + q] = tv[j][q];
  }
}

// ---------------------------------------------------------------------------
// K2b: column top-8, phase 2. One thread per (b,m): stream 32 sorted chunk
// lists (64 B coalesced each, early-break per list) into a register top-8.
// colsel[t] = int2(n, scaled-value bits (C*inv)).
// ---------------------------------------------------------------------------
__global__ __launch_bounds__(256) void k_coltop2(const ull* __restrict__ partial,
                                                 int2* __restrict__ colsel) {
  int t = blockIdx.x * 256 + threadIdx.x;     // b*NM + m
  if (t >= NB * NM) return;
  int b = t / NM, m = t % NM;
  ull top[8];
#pragma unroll
  for (int q = 0; q < 8; ++q) top[q] = 0;
  for (int c = 0; c < NCH; ++c) {
    const ull* src = partial + (((size_t)b * NCH + c) * NM + m) * 8;
    ull buf[8];
#pragma unroll
    for (int q = 0; q < 8; ++q) buf[q] = src[q];
    for (int q = 0; q < 8; ++q) {
      ull key = buf[q];
      if (key <= top[7]) break;               // list sorted desc -> rest smaller
      int pos = 8;
#pragma unroll
      for (int z = 7; z >= 0; --z) if (key > top[z]) pos = z;
#pragma unroll
      for (int z = 7; z >= 1; --z) if (z > pos) top[z] = top[z-1];
#pragma unroll
      for (int z = 0; z < 8; ++z) if (z == pos) top[z] = key;
    }
  }
#pragma unroll
  for (int q = 0; q < 8; ++q)
    colsel[(size_t)t * KK + q] =
        make_int2((int)~(unsigned)top[q], (int)(top[q] >> 32));
}

// ---------------------------------------------------------------------------
// K3 (fill): ZERO C reads — values come from rowsel/colsel. Base slots 0..7
// + non-duplicate extras (8+). pk arrays pre-filled with DUMMY_PAT.
// Arithmetic chains identical to prior rounds: (C*iv)*SCALE.
// ---------------------------------------------------------------------------
__global__ __launch_bounds__(256) void k_fill(const float* __restrict__ invnorms,
    const int2* __restrict__ rowsel, const int2* __restrict__ colsel,
    int* r_cnt, int* c_cnt, int2* __restrict__ r_pk, int2* __restrict__ c_pk) {
  int t = blockIdx.x * 256 + threadIdx.x;
  if (t >= NB * NN * KK) return;
  int k = t % KK; int bn = t / KK;
  int b = bn / NN; int n = bn % NN;
  float inv_bn = invnorms[bn];
  int2 rs = rowsel[t];                        // (m, raw C bits)
  int2 cs = colsel[t];                        // (n2, (C*inv) bits)
  {  // base row entry
    float v2 = __int_as_float(rs.y) * inv_bn * SCALE;
    r_pk[(size_t)bn * CAP + k] = make_int2(rs.x, __float_as_int(v2));
  }
  {  // base col entry (bn reinterpreted as b*NM+m)
    float v2 = __int_as_float(cs.y) * SCALE;
    c_pk[(size_t)bn * CAP + k] = make_int2(cs.x, __float_as_int(v2));
  }
  int m = n;                                  // extras: t = (b*NM+m)*KK + k
  {  // colsel entry (b,m,k): row n3 gains column m unless duplicate
    int n3 = cs.x;
    const int2* rl = rowsel + ((size_t)b * NN + n3) * KK;
    bool dup = false;
#pragma unroll
    for (int q = 0; q < KK; ++q) dup |= (rl[q].x == m);
    if (!dup) {
      int slot = 8 + atomicAdd(&r_cnt[(size_t)b * NN + n3], 1);
      if (slot < CAP) {
        float v2 = __int_as_float(cs.y) * SCALE;
        r_pk[((size_t)b * NN + n3) * CAP + slot] = make_int2(m, __float_as_int(v2));
      }
    }
  }
  {  // rowsel entry (b,n,k): column mm gains row n unless duplicate
    int mm = rs.x;
    const int2* cl = colsel + ((size_t)b * NM + mm) * KK;
    bool dup = false;
#pragma unroll
    for (int q = 0; q < KK; ++q) dup |= (cl[q].x == n);
    if (!dup) {
      int slot = 8 + atomicAdd(&c_cnt[(size_t)b * NM + mm], 1);
      if (slot < CAP) {
        float v2 = __int_as_float(rs.y) * inv_bn * SCALE;
        c_pk[((size_t)b * NM + mm) * CAP + slot] = make_int2(n, __float_as_int(v2));
      }
    }
  }
}

// ---------------------------------------------------------------------------
// K5: tagged pull-as-ready sparse Sinkhorn (R9 validated, UNCHANGED).
// ---------------------------------------------------------------------------
__global__ __launch_bounds__(TPB, 1) void k_sink_coop(
    const float* __restrict__ mu, const float* __restrict__ nu,
    const int2* __restrict__ r_pk, const int2* __restrict__ c_pk,
    ull* __restrict__ Upub, ull* __restrict__ Vpub,
    ull* errW, float* __restrict__ costpart) {
  const int blk = blockIdx.x;
  const int b = blk % NB, slice = blk / NB;
  const int tid = threadIdx.x;
  const int w = tid >> 6, lane = tid & 63;
  const int r = slice * RPB + tid;
  const bool has_r = (tid < RPB);             // NN == NM: same geometry

  // wave-resident sparse entries (persistent VGPRs)
  float rval[CAP], cval[CAP];
  unsigned ridx[CAP / 2], cidx[CAP / 2];
  float u = 0.f, vv = 0.f, lmu = 0.f, lnu = 0.f;
  if (has_r) {
    const int2* rp = r_pk + ((size_t)b * NN + r) * CAP;
    const int2* cp = c_pk + ((size_t)b * NM + r) * CAP;
#pragma unroll
    for (int i = 0; i < CAP; i += 2) {
      int2 e0 = rp[i], e1 = rp[i + 1];
      rval[i] = __int_as_float(e0.y); rval[i + 1] = __int_as_float(e1.y);
      unsigned i0 = min((unsigned)e0.x & 0xFFFFu, (unsigned)(NN - 1));  // clamp dummies
      unsigned i1 = min((unsigned)e1.x & 0xFFFFu, (unsigned)(NN - 1));
      ridx[i / 2] = i0 | (i1 << 16);
      int2 f0 = cp[i], f1 = cp[i + 1];
      cval[i] = __int_as_float(f0.y); cval[i + 1] = __int_as_float(f1.y);
      unsigned j0 = min((unsigned)f0.x & 0xFFFFu, (unsigned)(NN - 1));
      unsigned j1 = min((unsigned)f1.x & 0xFFFFu, (unsigned)(NN - 1));
      cidx[i / 2] = j0 | (j1 << 16);
    }
    lmu = FLOG2(mu[(size_t)b * NN + r] + 1e-8f);
    lnu = FLOG2(nu[(size_t)b * NM + r] + 1e-8f);
  }

  __shared__ float XL[NN];                    // staged U or V (12 KB)
  __shared__ float sred[TPB / 64];
  __shared__ float errl[BPB];
  int itf = 0;
  bool done = false;

  for (int it = 0; it < 100; ++it) {
    // ---- stage-A: XL <- V(it-1) (zeros at it==0); own slice from registers ----
    if (it == 0) {
      for (int i = tid; i < NN; i += TPB) XL[i] = 0.f;
    } else {
      if (has_r) XL[r] = vv;
      if (w != slice) {
        const ull* src = Vpub + (size_t)((it - 1) & 1) * (NB * NN)
                       + (size_t)b * NN + (size_t)w * RPB;
        pull_tagged(src, it, XL + w * RPB, lane);
      }
    }
    __syncthreads();

    // ---- compute-A: u update, publish tagged U ----
    float errp = 0.f;
    if (has_r) {
      float s = 0.f;
#pragma unroll
      for (int i = 0; i < CAP; ++i) {
        int ix = (ridx[i >> 1] >> ((i & 1) * 16)) & 0xFFFF;
        s += FEXP2(u + XL[ix] - rval[i]);
      }
      float un = lmu - FLOG2(1e-8f + s) + u;
      errp = fabsf(un - u);
      u = un;
      astore64(&Upub[(size_t)(it & 1) * (NB * NN) + (size_t)b * NN + r],
               ((ull)(unsigned)(it + 1) << 32) | __float_as_uint(u));
    }
#pragma unroll
    for (int o = 32; o; o >>= 1) errp += __shfl_down(errp, o);
    if (lane == 0) sred[w] = errp;
    __syncthreads();                          // also: XL(V) reads done -> safe to overwrite
    if (tid == 0) {
      float e = sred[0] + sred[1] + sred[2] + sred[3]
              + sred[4] + sred[5] + sred[6] + sred[7];
      astore64(&errW[(size_t)((it & 1) * NB + b) * BPB * 16 + slice * 16],
               ((ull)(unsigned)(it + 1) << 32) | __float_as_uint(e));
      errl[slice] = e;
    }

    // ---- stage-B: XL <- U(it); own slice from registers; err words ----
    if (has_r) XL[r] = u;
    if (w != slice) {
      const ull* src = Upub + (size_t)(it & 1) * (NB * NN)
                     + (size_t)b * NN + (size_t)w * RPB;
      pull_tagged(src, it + 1, XL + w * RPB, lane);
      if (lane == 0) {
        const ull* ep = errW + (size_t)((it & 1) * NB + b) * BPB * 16 + w * 16;
        ull x = aload64(ep);
        while ((int)(x >> 32) != it + 1) { __builtin_amdgcn_s_sleep(1); x = aload64(ep); }
        errl[w] = __uint_as_float((unsigned)x);
      }
    }
    __syncthreads();

    // ---- compute-B: uniform done decision, v update, publish tagged V ----
    float errtot = errl[0] + errl[1] + errl[2] + errl[3]
                 + errl[4] + errl[5] + errl[6] + errl[7];   // fixed order
    done = (errtot * UNSCALE < THRESH);
    if (has_r) {
      float s = 0.f;
#pragma unroll
      for (int i = 0; i < CAP; ++i) {
        int ix = (cidx[i >> 1] >> ((i & 1) * 16)) & 0xFFFF;
        s += FEXP2(vv + XL[ix] - cval[i]);
      }
      vv = lnu - FLOG2(1e-8f + s) + vv;
      astore64(&Vpub[(size_t)(it & 1) * (NB * NN) + (size_t)b * NN + r],
               ((ull)(unsigned)(it + 1) << 32) | __float_as_uint(vv));
    }
    __syncthreads();                          // XL(U) reads done -> next overwrite safe
    itf = it;
    if (done) break;                          // uniform across the batch
  }

  // ---- epilogue: XL <- V(itf); cost partial over own rows ----
  if (has_r) XL[r] = vv;
  if (w != slice) {
    const ull* src = Vpub + (size_t)(itf & 1) * (NB * NN)
                   + (size_t)b * NN + (size_t)w * RPB;
    pull_tagged(src, itf + 1, XL + w * RPB, lane);
  }
  __syncthreads();
  float cs = 0.f;
  if (has_r) {
#pragma unroll
    for (int i = 0; i < CAP; ++i) {
      int ix = (ridx[i >> 1] >> ((i & 1) * 16)) & 0xFFFF;
      float val = rval[i];
      cs += FEXP2(u + XL[ix] - val) * val;    // dummies give exp2(-huge)*big = 0
    }
  }
#pragma unroll
  for (int o = 32; o; o >>= 1) cs += __shfl_down(cs, o);
  if (lane == 0) sred[w] = cs;
  __syncthreads();
  if (tid == 0)
    costpart[b * BPB + slice] = sred[0] + sred[1] + sred[2] + sred[3]
                              + sred[4] + sred[5] + sred[6] + sred[7];
}

// Deterministic final reduction: fixed-order sums.
__global__ void k_final2(const float* __restrict__ costpart, float* __restrict__ out) {
  if (threadIdx.x == 0 && blockIdx.x == 0) {
    float tot = 0.f;
    for (int b = 0; b < NB; ++b) {
      float cb = 0.f;
      for (int s = 0; s < BPB; ++s) cb += costpart[b * BPB + s];
      tot += cb * UNSCALE;
    }
    out[0] = tot * (1.0f / NB);
  }
}

// ---------------------------------------------------------------------------
extern "C" void kernel_launch(void* const* d_in, const int* in_sizes, int n_in,
                              void* d_out, int out_size, void* d_ws, size_t ws_size,
                              hipStream_t stream) {
  const float* mu = (const float*)d_in[0];
  const float* nu = (const float*)d_in[1];
  const float* C  = (const float*)d_in[2];
  float* out = (float*)d_out;

  char* ws = (char*)d_ws;
  size_t off = 0;
  auto alloc = [&](size_t bytes) {
    void* p = ws + off;
    off += (bytes + 255) & ~(size_t)255;
    return p;
  };
  float* invnorms = (float*)alloc(sizeof(float) * NB * NN);
  int2*  rowsel   = (int2*) alloc(sizeof(int2)  * NB * NN * KK);     // (m, raw bits)
  int2*  colsel   = (int2*) alloc(sizeof(int2)  * NB * NM * KK);     // (n, scaled bits)
  ull*   partial  = (ull*)  alloc(sizeof(ull)   * NB * NCH * NM * 8); // 49 MB
  int2*  r_pk     = (int2*) alloc(sizeof(int2)  * NB * NN * CAP);
  int2*  c_pk     = (int2*) alloc(sizeof(int2)  * NB * NM * CAP);    // contiguous after r_pk
  // ---- zeroed region starts here (tags must reset every launch/replay) ----
  ull*   Upub     = (ull*)  alloc(sizeof(ull)   * 2 * NB * NN);      // tagged parity dbuf
  ull*   Vpub     = (ull*)  alloc(sizeof(ull)   * 2 * NB * NM);
  ull*   errW     = (ull*)  alloc(sizeof(ull)   * 2 * NB * BPB * 16);
  int*   r_cnt    = (int*)  alloc(sizeof(int)   * NB * NN);
  int*   c_cnt    = (int*)  alloc(sizeof(int)   * NB * NM);
  float* costpart = (float*)alloc(sizeof(float) * NB * BPB);
  (void)ws_size; (void)in_sizes; (void)n_in; (void)out_size;

  // pk arrays pre-filled with dummy pattern (val=3.39e38, idx clamped in sink)
  hipMemsetD32Async((hipDeviceptr_t)r_pk, (int)DUMMY_PAT,
                    (size_t)2 * NB * NN * CAP * 2, stream);
  size_t span = (size_t)((char*)costpart - (char*)Upub)
              + ((sizeof(float) * NB * BPB + 255) & ~(size_t)255);
  hipMemsetAsync(Upub, 0, span, stream);      // Upub..costpart (tags -> 0)

  hipLaunchKernelGGL(k_rowprep, dim3(NB * NN / 8), dim3(256), 0, stream,
                     C, invnorms, rowsel);
  hipLaunchKernelGGL(k_coltop1, dim3(12, NCH / 4, NB), dim3(256), 0, stream,
                     C, invnorms, partial);
  hipLaunchKernelGGL(k_coltop2, dim3((NB * NM + 255) / 256), dim3(256), 0, stream,
                     partial, colsel);
  int nthreads = NB * NN * KK;
  hipLaunchKernelGGL(k_fill, dim3((nthreads + 255) / 256), dim3(256), 0, stream,
                     invnorms, rowsel, colsel, r_cnt, c_cnt, r_pk, c_pk);

  void* args[] = { (void*)&mu, (void*)&nu, (void*)&r_pk, (void*)&c_pk,
                   (void*)&Upub, (void*)&Vpub, (void*)&errW, (void*)&costpart };
  hipLaunchCooperativeKernel((const void*)k_sink_coop, dim3(NBLK), dim3(TPB),
                             args, 0, stream);

  hipLaunchKernelGGL(k_final2, dim3(1), dim3(64), 0, stream, costpart, out);
}